// Round 8
// baseline (8428.523 us; speedup 1.0000x reference)
//
#include <hip/hip_runtime.h>
#include <hip/hip_bf16.h>

#define HID 1024
#define NH 4
#define HD 256
#define NCH 64
#define BB 4
#define LL 4096
#define ROWS (BB*LL)
#define SSIZE (BB*NH*HD*HD)

typedef __hip_bfloat16 bf16;

struct u16x4 { unsigned short x, y, z, w; };

__device__ __forceinline__ float bfu2f(unsigned short u) {
  return __uint_as_float(((unsigned int)u) << 16);
}
__device__ __forceinline__ unsigned short f2bfu(float f) {
  unsigned int x = __float_as_uint(f);
  return (unsigned short)((x + 0x7FFFu + ((x >> 16) & 1u)) >> 16);
}
__device__ __forceinline__ float ldv(const float* p) { return *p; }
__device__ __forceinline__ float ldv(const bf16* p) { return bfu2f(*(const unsigned short*)p); }
__device__ __forceinline__ float4 ld4(const float* p) { return *(const float4*)p; }
__device__ __forceinline__ float4 ld4(const bf16* p) {
  u16x4 u = *(const u16x4*)p;
  return make_float4(bfu2f(u.x), bfu2f(u.y), bfu2f(u.z), bfu2f(u.w));
}
__device__ __forceinline__ void st4(float* p, float4 v) { *(float4*)p = v; }
__device__ __forceinline__ void st4(bf16* p, float4 v) {
  u16x4 u; u.x = f2bfu(v.x); u.y = f2bfu(v.y); u.z = f2bfu(v.z); u.w = f2bfu(v.w);
  *(u16x4*)p = u;
}

// ---------------- beta = sigmoid(x @ Wb) ----------------
__global__ __launch_bounds__(256)
void beta_kernel(const float* __restrict__ x, const float* __restrict__ Wb,
                 float* __restrict__ beta) {
  const int wave = threadIdx.x >> 6, lane = threadIdx.x & 63;
  const int m = (blockIdx.x << 2) + wave;
  const float* xr = x + (size_t)m * HID;
  float a0 = 0.f, a1 = 0.f, a2 = 0.f, a3 = 0.f;
#pragma unroll
  for (int it = 0; it < 16; ++it) {
    int kk = lane + (it << 6);
    float xv = xr[kk];
    float4 w = *(const float4*)&Wb[kk << 2];
    a0 += xv * w.x; a1 += xv * w.y; a2 += xv * w.z; a3 += xv * w.w;
  }
#pragma unroll
  for (int off = 32; off; off >>= 1) {
    a0 += __shfl_xor(a0, off); a1 += __shfl_xor(a1, off);
    a2 += __shfl_xor(a2, off); a3 += __shfl_xor(a3, off);
  }
  if (lane == 0) {
    float4 r;
    r.x = 1.f / (1.f + expf(-a0)); r.y = 1.f / (1.f + expf(-a1));
    r.z = 1.f / (1.f + expf(-a2)); r.w = 1.f / (1.f + expf(-a3));
    *(float4*)&beta[m << 2] = r;
  }
}

// ------- fused GEMM (x@W) + causal depthwise conv(K=4) + SiLU (+beta for v) -------
// Block computes lin rows m0-3..m0+63 (halo) x 64 cols, conv in epilogue.
// MODE 0: q (store silu, unnormalized)  1: k (same)  2: v (store silu*beta)
template <int MODE, typename ST>
__global__ __launch_bounds__(256)
void gemm_conv(const float* __restrict__ A, const float* __restrict__ B,
               const float* __restrict__ cw, const float* __restrict__ beta,
               ST* __restrict__ out) {
  __shared__ float sm[68 * 68];
  float* As = sm;            // [k 0..31][r 0..66] stride 68
  float* Bs = sm + 2176;     // [k 0..31][c 0..63] stride 68
  const int m0 = blockIdx.x << 6, n0 = blockIdx.y << 6;
  const int tid = threadIdx.x;
  const int tr = tid >> 4, tc = tid & 15;
  float acc[5][4] = {{0.f}};
  for (int k0 = 0; k0 < HID; k0 += 32) {
#pragma unroll
    for (int it = 0; it < 3; ++it) {
      int idx = tid + (it << 8);
      if (idx < 536) {
        int r = idx >> 3, c4 = (idx & 7) << 2;
        int grow = m0 - 3 + r;
        float4 a = (grow >= 0) ? *(const float4*)&A[(size_t)grow * HID + k0 + c4]
                               : make_float4(0.f, 0.f, 0.f, 0.f);
        As[(c4 + 0) * 68 + r] = a.x; As[(c4 + 1) * 68 + r] = a.y;
        As[(c4 + 2) * 68 + r] = a.z; As[(c4 + 3) * 68 + r] = a.w;
      }
    }
#pragma unroll
    for (int it = 0; it < 2; ++it) {
      int idx = tid + (it << 8);
      int r2 = idx >> 4, c42 = (idx & 15) << 2;
      *(float4*)&Bs[r2 * 68 + c42] = *(const float4*)&B[(size_t)(k0 + r2) * HID + n0 + c42];
    }
    __syncthreads();
#pragma unroll
    for (int kk = 0; kk < 32; ++kk) {
      float4 b = *(float4*)&Bs[kk * 68 + (tc << 2)];
      float a0 = As[kk * 68 + tr];
      float a1 = As[kk * 68 + tr + 16];
      float a2 = As[kk * 68 + tr + 32];
      float a3 = As[kk * 68 + tr + 48];
      float a4 = (tr < 3) ? As[kk * 68 + tr + 64] : 0.f;
      acc[0][0] += a0*b.x; acc[0][1] += a0*b.y; acc[0][2] += a0*b.z; acc[0][3] += a0*b.w;
      acc[1][0] += a1*b.x; acc[1][1] += a1*b.y; acc[1][2] += a1*b.z; acc[1][3] += a1*b.w;
      acc[2][0] += a2*b.x; acc[2][1] += a2*b.y; acc[2][2] += a2*b.z; acc[2][3] += a2*b.w;
      acc[3][0] += a3*b.x; acc[3][1] += a3*b.y; acc[3][2] += a3*b.z; acc[3][3] += a3*b.w;
      acc[4][0] += a4*b.x; acc[4][1] += a4*b.y; acc[4][2] += a4*b.z; acc[4][3] += a4*b.w;
    }
    __syncthreads();
  }
  // dump lin tile: local row r = tr + 16*i  (global row m0-3+r)
#pragma unroll
  for (int i = 0; i < 5; ++i) {
    if (i < 4 || tr < 3) {
      int r = tr + (i << 4);
#pragma unroll
      for (int j = 0; j < 4; ++j) sm[r * 68 + (tc << 2) + j] = acc[i][j];
    }
  }
  __syncthreads();
  float wv[4][4];
#pragma unroll
  for (int j = 0; j < 4; ++j) {
    float4 t4 = *(const float4*)&cw[(n0 + (tc << 2) + j) << 2];
    wv[j][0] = t4.x; wv[j][1] = t4.y; wv[j][2] = t4.z; wv[j][3] = t4.w;
  }
  const int h = n0 >> 8;
#pragma unroll
  for (int u = 0; u < 4; ++u) {
    int orr = (tr << 2) + u;
    int R = m0 + orr;
    int l = R & (LL - 1);
    float y[4] = {0.f, 0.f, 0.f, 0.f};
#pragma unroll
    for (int t = 0; t < 4; ++t) {
      if (l - 3 + t >= 0) {
        const float* lr = &sm[(orr + t) * 68 + (tc << 2)];
#pragma unroll
        for (int j = 0; j < 4; ++j) y[j] += lr[j] * wv[j][t];
      }
    }
#pragma unroll
    for (int j = 0; j < 4; ++j) y[j] = y[j] / (1.f + expf(-y[j]));
    float4 o4;
    if (MODE == 2) {
      float bt = beta[(R << 2) + h];
      o4 = make_float4(y[0]*bt, y[1]*bt, y[2]*bt, y[3]*bt);
    } else {
      o4 = make_float4(y[0], y[1], y[2], y[3]);
    }
    st4(&out[(size_t)R * HID + n0 + (tc << 2)], o4);
  }
}

// ---- in-place L2 normalize over head_dim (wave = head) ----
template <typename ST>
__global__ __launch_bounds__(256)
void norm_kernel(ST* __restrict__ q) {
  const int row = blockIdx.x;
  const int ch = threadIdx.x << 2;
  ST* p = &q[(size_t)row * HID + ch];
  float4 v = ld4(p);
  float ss = v.x*v.x + v.y*v.y + v.z*v.z + v.w*v.w;
#pragma unroll
  for (int off = 32; off; off >>= 1) ss += __shfl_xor(ss, off);
  float inv = 1.f / sqrtf(ss);
  v.x *= inv; v.y *= inv; v.z *= inv; v.w *= inv;
  st4(p, v);
}

// ---- per-(b,n): A = (beta*k)@k^T over ALL channels, T0 = I - tril(A,-1),
//      exact reference recurrence, write T (64x64) to global ----
__global__ __launch_bounds__(256)
void chunkT_kernel(const float* __restrict__ k, const float* __restrict__ beta,
                   float* __restrict__ Tg) {
  __shared__ float T[64][68];
  __shared__ float S1[64][68];   // (beta*k)^T tile [dd][i]
  __shared__ float S2[64][68];   // k^T tile       [dd][j]
  __shared__ float row_s[64];
  const int bn = blockIdx.x;
  const size_t base = (size_t)bn * 64 * HID;
  const int tid = threadIdx.x;
  const int tr = tid >> 4, tc = tid & 15;
  float acc[4][4] = {{0.f}};
  for (int d0 = 0; d0 < HID; d0 += 64) {
    const int h = d0 >> 8;
#pragma unroll
    for (int p = 0; p < 4; ++p) {
      int rr = (tid >> 4) + (p << 4);
      int c4 = (tid & 15) << 2;
      float4 a = *(const float4*)&k[base + (size_t)rr * HID + d0 + c4];
      float bta = beta[(((bn << 6) + rr) << 2) + h];
      S2[c4 + 0][rr] = a.x; S2[c4 + 1][rr] = a.y;
      S2[c4 + 2][rr] = a.z; S2[c4 + 3][rr] = a.w;
      S1[c4 + 0][rr] = a.x * bta; S1[c4 + 1][rr] = a.y * bta;
      S1[c4 + 2][rr] = a.z * bta; S1[c4 + 3][rr] = a.w * bta;
    }
    __syncthreads();
#pragma unroll
    for (int dd = 0; dd < 64; ++dd) {
      float4 a = *(const float4*)&S1[dd][tr << 2];
      float4 b = *(const float4*)&S2[dd][tc << 2];
      acc[0][0] += a.x*b.x; acc[0][1] += a.x*b.y; acc[0][2] += a.x*b.z; acc[0][3] += a.x*b.w;
      acc[1][0] += a.y*b.x; acc[1][1] += a.y*b.y; acc[1][2] += a.y*b.z; acc[1][3] += a.y*b.w;
      acc[2][0] += a.z*b.x; acc[2][1] += a.z*b.y; acc[2][2] += a.z*b.z; acc[2][3] += a.z*b.w;
      acc[3][0] += a.w*b.x; acc[3][1] += a.w*b.y; acc[3][2] += a.w*b.z; acc[3][3] += a.w*b.w;
    }
    __syncthreads();
  }
#pragma unroll
  for (int i = 0; i < 4; ++i)
#pragma unroll
    for (int j = 0; j < 4; ++j) {
      int ri = (tr << 2) + i, cj = (tc << 2) + j;
      T[ri][cj] = (ri == cj) ? 1.f : (ri > cj ? -acc[i][j] : 0.f);
    }
  __syncthreads();
  for (int i = 1; i < 64; ++i) {
    if (tid < 64) row_s[tid] = T[i][tid];
    __syncthreads();
    if (tid < 64) {
      float a = 0.f;
#pragma unroll 8
      for (int j = 0; j < 64; ++j) a += row_s[j] * T[j][tid];
      if (tid < i) T[i][tid] = row_s[tid] + a;
    }
    __syncthreads();
  }
#pragma unroll
  for (int ii = 0; ii < 4; ++ii) {
    int off = (tid << 4) + (ii << 2);
    int c = off >> 6, j = off & 63;
    *(float4*)&Tg[(size_t)bn * 4096 + off] = *(const float4*)&T[c][j];
  }
}

// ---- P,R via ct[j,ch] = sum_c T[c,j]*k[c,ch]:  P = sum_j beta*k*ct, R = sum_j v*ct ----
template <typename ST>
__global__ __launch_bounds__(256)
void prct_kernel(const float* __restrict__ k, const ST* __restrict__ v,
                 const float* __restrict__ beta, const float* __restrict__ Tg,
                 float* __restrict__ P, float* __restrict__ R) {
  __shared__ float Ts[4096];
  __shared__ float bs[64];
  const int bn = blockIdx.x >> 2, h = blockIdx.x & 3;
  const int tid = threadIdx.x;
#pragma unroll
  for (int ii = 0; ii < 4; ++ii) {
    int off = (tid << 4) + (ii << 2);
    *(float4*)&Ts[off] = *(const float4*)&Tg[(size_t)bn * 4096 + off];
  }
  if (tid < 64) bs[tid] = beta[(((bn << 6) + tid) << 2) + h];
  __syncthreads();
  const int ch = (h << 8) + tid;
  const size_t base = (size_t)bn * 64 * HID;
  float ct[64];
#pragma unroll
  for (int j = 0; j < 64; ++j) ct[j] = 0.f;
  for (int c = 0; c < 64; ++c) {
    float kc = k[base + (size_t)c * HID + ch];
#pragma unroll
    for (int j = 0; j < 64; ++j) ct[j] += Ts[(c << 6) + j] * kc;
  }
  float p = 0.f, r = 0.f;
#pragma unroll
  for (int j = 0; j < 64; ++j) {
    float kj = k[base + (size_t)j * HID + ch];
    float vj = ldv(&v[base + (size_t)j * HID + ch]);
    p += bs[j] * kj * ct[j];
    r += vj * ct[j];
  }
  P[(size_t)bn * HID + ch] = p;
  R[(size_t)bn * HID + ch] = r;
}

// ---- diagonal scan: Sd' = Sd*(1-P) + R ; stores pre-chunk Sd ----
__global__ __launch_bounds__(256)
void scan_kernel(const float* __restrict__ P, const float* __restrict__ R,
                 float* __restrict__ Sdp) {
  const int b = blockIdx.x >> 2;
  const int ch = ((blockIdx.x & 3) << 8) + threadIdx.x;
  float S = 0.f;
  for (int n = 0; n < 64; ++n) {
    Sdp[(size_t)((n << 2) + b) * HID + ch] = S;
    float p = P[(size_t)((b << 6) + n) * HID + ch];
    float r = R[(size_t)((b << 6) + n) * HID + ch];
    S = S * (1.f - p) + r;
  }
}

// ---- osm[(bn,c),ch] = sum_j T[c,j]*(v[j,ch] - beta[j]*k[j,ch]*Sd[ch]) for c=0..3 ----
template <typename ST>
__global__ __launch_bounds__(256)
void osm_kernel(const float* __restrict__ k, const ST* __restrict__ v,
                const float* __restrict__ beta, const float* __restrict__ Tg,
                const float* __restrict__ Sdp, float* __restrict__ osm) {
  __shared__ float Ts4[4][64];
  __shared__ float bs[64];
  const int bn = blockIdx.x >> 2, h = blockIdx.x & 3;
  const int b = bn >> 6, n = bn & 63;
  const int tid = threadIdx.x;
  Ts4[tid >> 6][tid & 63] = Tg[(size_t)bn * 4096 + tid];
  if (tid < 64) bs[tid] = beta[(((bn << 6) + tid) << 2) + h];
  __syncthreads();
  const int ch = (h << 8) + tid;
  const size_t base = (size_t)bn * 64 * HID;
  float sd = Sdp[(size_t)((n << 2) + b) * HID + ch];
  float a0 = 0.f, a1 = 0.f, a2 = 0.f, a3 = 0.f;
  for (int j = 0; j < 64; ++j) {
    float kj = k[base + (size_t)j * HID + ch];
    float vj = ldv(&v[base + (size_t)j * HID + ch]);
    float w = vj - bs[j] * kj * sd;
    a0 += Ts4[0][j] * w; a1 += Ts4[1][j] * w;
    a2 += Ts4[2][j] * w; a3 += Ts4[3][j] * w;
  }
  osm[((size_t)(bn << 2) + 0) * HID + ch] = a0;
  osm[((size_t)(bn << 2) + 1) * HID + ch] = a1;
  osm[((size_t)(bn << 2) + 2) * HID + ch] = a2;
  osm[((size_t)(bn << 2) + 3) * HID + ch] = a3;
}

// ---- Ai[b,n,c] = sum_{ch} q*k for c=0..3 ----
template <typename ST>
__global__ __launch_bounds__(256)
void ai_kernel(const ST* __restrict__ q, const float* __restrict__ k,
               float* __restrict__ Ai) {
  const int bn = blockIdx.x;
  const int b = bn >> 6;
  const int wave = threadIdx.x >> 6, lane = threadIdx.x & 63;
  const size_t roff = ((size_t)bn * 64 + wave) * HID;
  float s = 0.f;
#pragma unroll
  for (int it = 0; it < 4; ++it) {
    int d = (lane << 2) + (it << 8);
    float4 a = ld4(&q[roff + d]);
    float4 b4 = *(const float4*)&k[roff + d];
    s += a.x*b4.x + a.y*b4.y + a.z*b4.z + a.w*b4.w;
  }
#pragma unroll
  for (int off = 32; off; off >>= 1) s += __shfl_xor(s, off);
  if (lane == 0) Ai[(bn << 2) + wave] = (wave <= b) ? s : 0.f;
}

// ---- o = q*Sd + (c<=b)*Ai*osm, RMSNorm(head)*g ; in-place over q ----
template <typename ST>
__global__ __launch_bounds__(256)
void o_kernel(ST* __restrict__ q, const float* __restrict__ Sdp,
              const float* __restrict__ osm, const float* __restrict__ Ai,
              const float* __restrict__ g) {
  const int row = blockIdx.x;
  const int b = row >> 12;
  const int l = row & (LL - 1);
  const int n = l >> 6, c = l & 63;
  const int ch = threadIdx.x << 2;
  const size_t ro = (size_t)row * HID;
  float4 qv = ld4(&q[ro + ch]);
  float4 sd = *(const float4*)&Sdp[(size_t)((n << 2) + b) * HID + ch];
  float ox = qv.x*sd.x, oy = qv.y*sd.y, oz = qv.z*sd.z, ow = qv.w*sd.w;
  if (c <= b) {
    int bn = (b << 6) + n;
    float a = Ai[(bn << 2) + c];
    float4 u = *(const float4*)&osm[((size_t)(bn << 2) + c) * HID + ch];
    ox += a * u.x; oy += a * u.y; oz += a * u.z; ow += a * u.w;
  }
  float ss = ox*ox + oy*oy + oz*oz + ow*ow;
#pragma unroll
  for (int off = 32; off; off >>= 1) ss += __shfl_xor(ss, off);
  float scale = 1.f / sqrtf(ss * (1.f / HD) + 1e-5f);
  float4 gv = *(const float4*)&g[ch & (HD - 1)];
  st4(&q[ro + ch], make_float4(ox*scale*gv.x, oy*scale*gv.y, oz*scale*gv.z, ow*scale*gv.w));
}

// ---- out = o @ Wo ----
template <typename ST>
__global__ __launch_bounds__(256)
void gemm_out(const ST* __restrict__ A, const float* __restrict__ B,
              float* __restrict__ C) {
  __shared__ float As[32][68];
  __shared__ float Bs[32][68];
  const int m0 = blockIdx.x << 6, n0 = blockIdx.y << 6;
  const int tid = threadIdx.x;
  const int tr = tid >> 4, tc = tid & 15;
  float acc[4][4] = {{0.f}};
  for (int k0 = 0; k0 < HID; k0 += 32) {
#pragma unroll
    for (int i = 0; i < 2; ++i) {
      int idx = tid + (i << 8);
      int r = idx >> 3, c4 = (idx & 7) << 2;
      float4 a = ld4(&A[(size_t)(m0 + r) * HID + k0 + c4]);
      As[c4 + 0][r] = a.x; As[c4 + 1][r] = a.y; As[c4 + 2][r] = a.z; As[c4 + 3][r] = a.w;
      int r2 = idx >> 4, c42 = (idx & 15) << 2;
      *(float4*)&Bs[r2][c42] = *(const float4*)&B[(size_t)(k0 + r2) * HID + n0 + c42];
    }
    __syncthreads();
#pragma unroll
    for (int kk = 0; kk < 32; ++kk) {
      float4 a = *(const float4*)&As[kk][tr << 2];
      float4 b = *(const float4*)&Bs[kk][tc << 2];
      acc[0][0] += a.x*b.x; acc[0][1] += a.x*b.y; acc[0][2] += a.x*b.z; acc[0][3] += a.x*b.w;
      acc[1][0] += a.y*b.x; acc[1][1] += a.y*b.y; acc[1][2] += a.y*b.z; acc[1][3] += a.y*b.w;
      acc[2][0] += a.z*b.x; acc[2][1] += a.z*b.y; acc[2][2] += a.z*b.z; acc[2][3] += a.z*b.w;
      acc[3][0] += a.w*b.x; acc[3][1] += a.w*b.y; acc[3][2] += a.w*b.z; acc[3][3] += a.w*b.w;
    }
    __syncthreads();
  }
#pragma unroll
  for (int i = 0; i < 4; ++i)
    *(float4*)&C[(size_t)(m0 + (tr << 2) + i) * HID + n0 + (tc << 2)] =
        make_float4(acc[i][0], acc[i][1], acc[i][2], acc[i][3]);
}

// ---- final S: block (bh, e-quarter); per chunk recompute u = T@(v - beta*k*Sd) ----
template <typename ST>
__global__ __launch_bounds__(256)
void sfinal_kernel(const float* __restrict__ k, const ST* __restrict__ v,
                   const float* __restrict__ beta, const float* __restrict__ Tg,
                   const float* __restrict__ Sdp, float* __restrict__ Sout) {
  __shared__ float Ts[4096];
  __shared__ float va[64][68];
  __shared__ float us[64][68];
  __shared__ float bs[64];
  const int bh = blockIdx.x >> 2, eq = blockIdx.x & 3;
  const int b = bh >> 2, h = bh & 3;
  const int e0 = eq << 6;
  const int tid = threadIdx.x;
  float4 acc[16];
#pragma unroll
  for (int j4 = 0; j4 < 16; ++j4) acc[j4] = make_float4(0.f, 0.f, 0.f, 0.f);
  for (int n = 0; n < 64; ++n) {
    const int bn = (b << 6) + n;
    const size_t base = (size_t)bn * 64 * HID;
    __syncthreads();
#pragma unroll
    for (int ii = 0; ii < 4; ++ii) {
      int off = (tid << 4) + (ii << 2);
      *(float4*)&Ts[off] = *(const float4*)&Tg[(size_t)bn * 4096 + off];
    }
    if (tid < 64) bs[tid] = beta[(((bn << 6) + tid) << 2) + h];
    __syncthreads();
#pragma unroll
    for (int p = 0; p < 16; ++p) {
      int idx = tid + (p << 8);
      int rr = idx >> 6, e = idx & 63;
      int chg = (h << 8) + e0 + e;
      float sdv = Sdp[(size_t)((n << 2) + b) * HID + chg];
      float kj = k[base + (size_t)rr * HID + chg];
      float vj = ldv(&v[base + (size_t)rr * HID + chg]);
      va[rr][e] = vj - bs[rr] * kj * sdv;
    }
    __syncthreads();
#pragma unroll
    for (int p = 0; p < 16; ++p) {
      int idx = tid + (p << 8);
      int c = idx >> 6, e = idx & 63;
      float s = 0.f;
#pragma unroll 16
      for (int j = 0; j < 64; ++j) s += Ts[(c << 6) + j] * va[j][e];
      us[c][e] = s;
    }
    __syncthreads();
    const int chd = (h << 8) + tid;
    for (int c = 0; c < 64; ++c) {
      float kv = k[base + (size_t)c * HID + chd];
#pragma unroll
      for (int j4 = 0; j4 < 16; ++j4) {
        float4 u4 = *(const float4*)&us[c][j4 << 2];
        acc[j4].x += kv*u4.x; acc[j4].y += kv*u4.y;
        acc[j4].z += kv*u4.z; acc[j4].w += kv*u4.w;
      }
    }
  }
  const size_t ob = ((size_t)(bh << 8) + tid) * HD + e0;
#pragma unroll
  for (int j4 = 0; j4 < 16; ++j4)
    *(float4*)&Sout[ob + (j4 << 2)] = acc[j4];
}

template <typename ST>
static void run_pipeline(const float* x, const float* Wq, const float* Wk,
                         const float* Wv, const float* Wb, const float* cq,
                         const float* ck, const float* cv, const float* g,
                         const float* Wo, float* out, float* Sout, float* kbuf,
                         float* Tg, float* betab, float* Aib, float* Pb,
                         float* Rb, float* Sdp, float* osmb, ST* qbuf, ST* vbuf,
                         hipStream_t stream) {
  dim3 gg(ROWS / 64, HID / 64);
  beta_kernel<<<ROWS / 4, 256, 0, stream>>>(x, Wb, betab);
  gemm_conv<0, ST><<<gg, 256, 0, stream>>>(x, Wq, cq, nullptr, qbuf);
  norm_kernel<ST><<<ROWS, 256, 0, stream>>>(qbuf);
  gemm_conv<1, float><<<gg, 256, 0, stream>>>(x, Wk, ck, nullptr, kbuf);
  norm_kernel<float><<<ROWS, 256, 0, stream>>>(kbuf);
  gemm_conv<2, ST><<<gg, 256, 0, stream>>>(x, Wv, cv, betab, vbuf);
  chunkT_kernel<<<BB * NCH, 256, 0, stream>>>(kbuf, betab, Tg);
  prct_kernel<ST><<<BB * NCH * NH, 256, 0, stream>>>(kbuf, vbuf, betab, Tg, Pb, Rb);
  scan_kernel<<<16, 256, 0, stream>>>(Pb, Rb, Sdp);
  osm_kernel<ST><<<BB * NCH * NH, 256, 0, stream>>>(kbuf, vbuf, betab, Tg, Sdp, osmb);
  ai_kernel<ST><<<BB * NCH, 256, 0, stream>>>(qbuf, kbuf, Aib);
  o_kernel<ST><<<ROWS, 256, 0, stream>>>(qbuf, Sdp, osmb, Aib, g);
  gemm_out<ST><<<gg, 256, 0, stream>>>(qbuf, Wo, out);
  sfinal_kernel<ST><<<64, 256, 0, stream>>>(kbuf, vbuf, betab, Tg, Sdp, Sout);
}

extern "C" void kernel_launch(void* const* d_in, const int* in_sizes, int n_in,
                              void* d_out, int out_size, void* d_ws, size_t ws_size,
                              hipStream_t stream) {
  const float* x  = (const float*)d_in[0];
  const float* Wq = (const float*)d_in[1];
  const float* Wk = (const float*)d_in[2];
  const float* Wv = (const float*)d_in[3];
  const float* Wb = (const float*)d_in[4];
  const float* cq = (const float*)d_in[5];
  const float* ck = (const float*)d_in[6];
  const float* cv = (const float*)d_in[7];
  const float* g  = (const float*)d_in[8];
  const float* Wo = (const float*)d_in[9];
  float* out  = (float*)d_out;
  float* Sout = out + (size_t)ROWS * HID;

  const size_t F = (size_t)ROWS * HID;
  char* w = (char*)d_ws;
  float* kbuf  = (float*)w;  w += F * 4;
  float* Tg    = (float*)w;  w += (size_t)BB * NCH * 4096 * 4;
  float* betab = (float*)w;  w += (size_t)ROWS * NH * 4;
  float* Aib   = (float*)w;  w += (size_t)BB * NCH * 4 * 4;
  float* Pb    = (float*)w;  w += (size_t)BB * NCH * HID * 4;
  float* Rb    = (float*)w;  w += (size_t)BB * NCH * HID * 4;
  float* Sdp   = (float*)w;  w += (size_t)BB * NCH * HID * 4;
  float* osmb  = (float*)w;  w += (size_t)BB * NCH * 4 * HID * 4;
  char* qv = w;
  const size_t fixed = (size_t)(qv - (char*)d_ws);
  const size_t needA = fixed + 2 * F * sizeof(float);
  const size_t needB = fixed + 2 * F * sizeof(bf16);

  if (ws_size >= needA) {
    float* qbuf = (float*)qv;
    float* vbuf = (float*)(qv + F * sizeof(float));
    run_pipeline<float>(x, Wq, Wk, Wv, Wb, cq, ck, cv, g, Wo, out, Sout, kbuf,
                        Tg, betab, Aib, Pb, Rb, Sdp, osmb, qbuf, vbuf, stream);
  } else if (ws_size >= needB) {
    bf16* qbuf = (bf16*)qv;
    bf16* vbuf = (bf16*)(qv + F * sizeof(bf16));
    run_pipeline<bf16>(x, Wq, Wk, Wv, Wb, cq, ck, cv, g, Wo, out, Sout, kbuf,
                       Tg, betab, Aib, Pb, Rb, Sdp, osmb, qbuf, vbuf, stream);
  }
  // else: workspace too small for any tier — leave output untouched.
}

// Round 9
// 2337.086 us; speedup vs baseline: 3.6064x; 3.6064x over previous
//
#include <hip/hip_runtime.h>
#include <hip/hip_bf16.h>

#define HID 1024
#define NH 4
#define HD 256
#define NCH 64
#define BB 4
#define LL 4096
#define ROWS (BB*LL)
#define SSIZE (BB*NH*HD*HD)

typedef __hip_bfloat16 bf16;

struct u16x4 { unsigned short x, y, z, w; };

__device__ __forceinline__ float bfu2f(unsigned short u) {
  return __uint_as_float(((unsigned int)u) << 16);
}
__device__ __forceinline__ unsigned short f2bfu(float f) {
  unsigned int x = __float_as_uint(f);
  return (unsigned short)((x + 0x7FFFu + ((x >> 16) & 1u)) >> 16);
}
__device__ __forceinline__ float ldv(const float* p) { return *p; }
__device__ __forceinline__ float ldv(const bf16* p) { return bfu2f(*(const unsigned short*)p); }
__device__ __forceinline__ float4 ld4(const float* p) { return *(const float4*)p; }
__device__ __forceinline__ float4 ld4(const bf16* p) {
  u16x4 u = *(const u16x4*)p;
  return make_float4(bfu2f(u.x), bfu2f(u.y), bfu2f(u.z), bfu2f(u.w));
}
__device__ __forceinline__ void st4(float* p, float4 v) { *(float4*)p = v; }
__device__ __forceinline__ void st4(bf16* p, float4 v) {
  u16x4 u; u.x = f2bfu(v.x); u.y = f2bfu(v.y); u.z = f2bfu(v.z); u.w = f2bfu(v.w);
  *(u16x4*)p = u;
}

// ---------------- beta = sigmoid(x @ Wb) ----------------
__global__ __launch_bounds__(256)
void beta_kernel(const float* __restrict__ x, const float* __restrict__ Wb,
                 float* __restrict__ beta) {
  const int wave = threadIdx.x >> 6, lane = threadIdx.x & 63;
  const int m = (blockIdx.x << 2) + wave;
  const float* xr = x + (size_t)m * HID;
  float a0 = 0.f, a1 = 0.f, a2 = 0.f, a3 = 0.f;
#pragma unroll
  for (int it = 0; it < 16; ++it) {
    int kk = lane + (it << 6);
    float xv = xr[kk];
    float4 w = *(const float4*)&Wb[kk << 2];
    a0 += xv * w.x; a1 += xv * w.y; a2 += xv * w.z; a3 += xv * w.w;
  }
#pragma unroll
  for (int off = 32; off; off >>= 1) {
    a0 += __shfl_xor(a0, off); a1 += __shfl_xor(a1, off);
    a2 += __shfl_xor(a2, off); a3 += __shfl_xor(a3, off);
  }
  if (lane == 0) {
    float4 r;
    r.x = 1.f / (1.f + expf(-a0)); r.y = 1.f / (1.f + expf(-a1));
    r.z = 1.f / (1.f + expf(-a2)); r.w = 1.f / (1.f + expf(-a3));
    *(float4*)&beta[m << 2] = r;
  }
}

// ---- 128x128 fp32 GEMM, 8x8/thread (split 4+4), C = A(M,1024)@B(1024,1024) ----
template <typename AT>
__global__ __launch_bounds__(256)
void gemm128(const AT* __restrict__ A, const float* __restrict__ B,
             float* __restrict__ C) {
  __shared__ float As[16][132];   // [k][m], transposed
  __shared__ float Bs[16][128];   // [k][n]
  const int m0 = blockIdx.x << 7, n0 = blockIdx.y << 7;
  const int tid = threadIdx.x;
  const int tr = tid >> 4, tc = tid & 15;
  float acc[8][8] = {{0.f}};
  for (int k0 = 0; k0 < HID; k0 += 16) {
#pragma unroll
    for (int it = 0; it < 2; ++it) {
      int idx = tid + (it << 8);
      int r = idx >> 2, c4 = (idx & 3) << 2;
      float4 a = ld4(&A[(size_t)(m0 + r) * HID + k0 + c4]);
      As[c4 + 0][r] = a.x; As[c4 + 1][r] = a.y;
      As[c4 + 2][r] = a.z; As[c4 + 3][r] = a.w;
      int r2 = idx >> 5, c42 = (idx & 31) << 2;
      *(float4*)&Bs[r2][c42] = *(const float4*)&B[(size_t)(k0 + r2) * HID + n0 + c42];
    }
    __syncthreads();
#pragma unroll
    for (int kk = 0; kk < 16; ++kk) {
      float4 a0 = *(const float4*)&As[kk][tr << 2];
      float4 a1 = *(const float4*)&As[kk][64 + (tr << 2)];
      float4 b0 = *(const float4*)&Bs[kk][tc << 2];
      float4 b1 = *(const float4*)&Bs[kk][64 + (tc << 2)];
      float av[8] = {a0.x, a0.y, a0.z, a0.w, a1.x, a1.y, a1.z, a1.w};
      float bv[8] = {b0.x, b0.y, b0.z, b0.w, b1.x, b1.y, b1.z, b1.w};
#pragma unroll
      for (int i = 0; i < 8; ++i)
#pragma unroll
        for (int j = 0; j < 8; ++j) acc[i][j] += av[i] * bv[j];
    }
    __syncthreads();
  }
#pragma unroll
  for (int half = 0; half < 2; ++half)
#pragma unroll
    for (int i = 0; i < 4; ++i) {
      int row = m0 + (half << 6) + (tr << 2) + i;
      float* cr = &C[(size_t)row * HID + n0];
      *(float4*)&cr[tc << 2] =
          make_float4(acc[(half<<2)+i][0], acc[(half<<2)+i][1],
                      acc[(half<<2)+i][2], acc[(half<<2)+i][3]);
      *(float4*)&cr[64 + (tc << 2)] =
          make_float4(acc[(half<<2)+i][4], acc[(half<<2)+i][5],
                      acc[(half<<2)+i][6], acc[(half<<2)+i][7]);
    }
}

// ------- causal depthwise conv(K=4) + SiLU (+L2 norm / +beta) -------
// MODE 0: q (normalize)  1: k (normalize)  2: v (silu*beta)
template <int MODE, typename ST>
__global__ __launch_bounds__(256)
void conv_kernel(const float* __restrict__ lin, const float* __restrict__ w,
                 const float* __restrict__ beta, ST* __restrict__ out) {
  const int row = blockIdx.x;
  const int l = row & (LL - 1);
  const int tid = threadIdx.x;
  const int ch = tid << 2;
  float wv[4][4];
#pragma unroll
  for (int j = 0; j < 4; ++j) {
    float4 t4 = *(const float4*)&w[(ch + j) << 2];
    wv[j][0] = t4.x; wv[j][1] = t4.y; wv[j][2] = t4.z; wv[j][3] = t4.w;
  }
  float y[4] = {0.f, 0.f, 0.f, 0.f};
#pragma unroll
  for (int t = 0; t < 4; ++t) {
    if (l - 3 + t >= 0) {
      float4 xv = *(const float4*)&lin[(size_t)(row - 3 + t) * HID + ch];
      y[0] += xv.x * wv[0][t]; y[1] += xv.y * wv[1][t];
      y[2] += xv.z * wv[2][t]; y[3] += xv.w * wv[3][t];
    }
  }
#pragma unroll
  for (int j = 0; j < 4; ++j) y[j] = y[j] / (1.f + expf(-y[j]));   // SiLU
  float scale;
  if (MODE < 2) {
    float ss = y[0]*y[0] + y[1]*y[1] + y[2]*y[2] + y[3]*y[3];
#pragma unroll
    for (int off = 32; off; off >>= 1) ss += __shfl_xor(ss, off);  // wave = head
    scale = 1.f / sqrtf(ss);
  } else {
    scale = beta[(row << 2) + (tid >> 6)];
  }
  st4(&out[(size_t)row * HID + ch],
      make_float4(y[0]*scale, y[1]*scale, y[2]*scale, y[3]*scale));
}

// ---- per-(b,n): A = (beta*k)@k^T, T0 = I - tril(A,-1), ref recurrence, store T ----
__global__ __launch_bounds__(256)
void chunkT_kernel(const float* __restrict__ k, const float* __restrict__ beta,
                   float* __restrict__ Tg) {
  __shared__ float T[64][68];
  __shared__ float S1[64][68];
  __shared__ float S2[64][68];
  __shared__ float row_s[64];
  const int bn = blockIdx.x;
  const size_t base = (size_t)bn * 64 * HID;
  const int tid = threadIdx.x;
  const int tr = tid >> 4, tc = tid & 15;
  float acc[4][4] = {{0.f}};
  for (int d0 = 0; d0 < HID; d0 += 64) {
    const int h = d0 >> 8;
#pragma unroll
    for (int p = 0; p < 4; ++p) {
      int rr = (tid >> 4) + (p << 4);
      int c4 = (tid & 15) << 2;
      float4 a = *(const float4*)&k[base + (size_t)rr * HID + d0 + c4];
      float bta = beta[(((bn << 6) + rr) << 2) + h];
      S2[c4 + 0][rr] = a.x; S2[c4 + 1][rr] = a.y;
      S2[c4 + 2][rr] = a.z; S2[c4 + 3][rr] = a.w;
      S1[c4 + 0][rr] = a.x * bta; S1[c4 + 1][rr] = a.y * bta;
      S1[c4 + 2][rr] = a.z * bta; S1[c4 + 3][rr] = a.w * bta;
    }
    __syncthreads();
#pragma unroll
    for (int dd = 0; dd < 64; ++dd) {
      float4 a = *(const float4*)&S1[dd][tr << 2];
      float4 b = *(const float4*)&S2[dd][tc << 2];
      acc[0][0] += a.x*b.x; acc[0][1] += a.x*b.y; acc[0][2] += a.x*b.z; acc[0][3] += a.x*b.w;
      acc[1][0] += a.y*b.x; acc[1][1] += a.y*b.y; acc[1][2] += a.y*b.z; acc[1][3] += a.y*b.w;
      acc[2][0] += a.z*b.x; acc[2][1] += a.z*b.y; acc[2][2] += a.z*b.z; acc[2][3] += a.z*b.w;
      acc[3][0] += a.w*b.x; acc[3][1] += a.w*b.y; acc[3][2] += a.w*b.z; acc[3][3] += a.w*b.w;
    }
    __syncthreads();
  }
#pragma unroll
  for (int i = 0; i < 4; ++i)
#pragma unroll
    for (int j = 0; j < 4; ++j) {
      int ri = (tr << 2) + i, cj = (tc << 2) + j;
      T[ri][cj] = (ri == cj) ? 1.f : (ri > cj ? -acc[i][j] : 0.f);
    }
  __syncthreads();
  for (int i = 1; i < 64; ++i) {
    if (tid < 64) row_s[tid] = T[i][tid];
    __syncthreads();
    if (tid < 64) {
      float a = 0.f;
#pragma unroll 8
      for (int j = 0; j < 64; ++j) a += row_s[j] * T[j][tid];
      if (tid < i) T[i][tid] = row_s[tid] + a;
    }
    __syncthreads();
  }
#pragma unroll
  for (int ii = 0; ii < 4; ++ii) {
    int off = (tid << 4) + (ii << 2);
    int c = off >> 6, j = off & 63;
    *(float4*)&Tg[(size_t)bn * 4096 + off] = *(const float4*)&T[c][j];
  }
}

// ---- P,R via ct[j,ch] = sum_c T[c,j]*k[c,ch] ----
template <typename ST>
__global__ __launch_bounds__(256)
void prct_kernel(const float* __restrict__ k, const ST* __restrict__ v,
                 const float* __restrict__ beta, const float* __restrict__ Tg,
                 float* __restrict__ P, float* __restrict__ R) {
  __shared__ float Ts[4096];
  __shared__ float bs[64];
  const int bn = blockIdx.x >> 2, h = blockIdx.x & 3;
  const int tid = threadIdx.x;
#pragma unroll
  for (int ii = 0; ii < 4; ++ii) {
    int off = (tid << 4) + (ii << 2);
    *(float4*)&Ts[off] = *(const float4*)&Tg[(size_t)bn * 4096 + off];
  }
  if (tid < 64) bs[tid] = beta[(((bn << 6) + tid) << 2) + h];
  __syncthreads();
  const int ch = (h << 8) + tid;
  const size_t base = (size_t)bn * 64 * HID;
  float ct[64];
#pragma unroll
  for (int j = 0; j < 64; ++j) ct[j] = 0.f;
  for (int c = 0; c < 64; ++c) {
    float kc = k[base + (size_t)c * HID + ch];
#pragma unroll
    for (int j = 0; j < 64; ++j) ct[j] += Ts[(c << 6) + j] * kc;
  }
  float p = 0.f, r = 0.f;
#pragma unroll
  for (int j = 0; j < 64; ++j) {
    float kj = k[base + (size_t)j * HID + ch];
    float vj = ldv(&v[base + (size_t)j * HID + ch]);
    p += bs[j] * kj * ct[j];
    r += vj * ct[j];
  }
  P[(size_t)bn * HID + ch] = p;
  R[(size_t)bn * HID + ch] = r;
}

// ---- diagonal scan ----
__global__ __launch_bounds__(256)
void scan_kernel(const float* __restrict__ P, const float* __restrict__ R,
                 float* __restrict__ Sdp) {
  const int b = blockIdx.x >> 2;
  const int ch = ((blockIdx.x & 3) << 8) + threadIdx.x;
  float S = 0.f;
  for (int n = 0; n < 64; ++n) {
    Sdp[(size_t)((n << 2) + b) * HID + ch] = S;
    float p = P[(size_t)((b << 6) + n) * HID + ch];
    float r = R[(size_t)((b << 6) + n) * HID + ch];
    S = S * (1.f - p) + r;
  }
}

// ---- osm rows c=0..3 ----
template <typename ST>
__global__ __launch_bounds__(256)
void osm_kernel(const float* __restrict__ k, const ST* __restrict__ v,
                const float* __restrict__ beta, const float* __restrict__ Tg,
                const float* __restrict__ Sdp, float* __restrict__ osm) {
  __shared__ float Ts4[4][64];
  __shared__ float bs[64];
  const int bn = blockIdx.x >> 2, h = blockIdx.x & 3;
  const int b = bn >> 6, n = bn & 63;
  const int tid = threadIdx.x;
  Ts4[tid >> 6][tid & 63] = Tg[(size_t)bn * 4096 + tid];
  if (tid < 64) bs[tid] = beta[(((bn << 6) + tid) << 2) + h];
  __syncthreads();
  const int ch = (h << 8) + tid;
  const size_t base = (size_t)bn * 64 * HID;
  float sd = Sdp[(size_t)((n << 2) + b) * HID + ch];
  float a0 = 0.f, a1 = 0.f, a2 = 0.f, a3 = 0.f;
  for (int j = 0; j < 64; ++j) {
    float kj = k[base + (size_t)j * HID + ch];
    float vj = ldv(&v[base + (size_t)j * HID + ch]);
    float w = vj - bs[j] * kj * sd;
    a0 += Ts4[0][j] * w; a1 += Ts4[1][j] * w;
    a2 += Ts4[2][j] * w; a3 += Ts4[3][j] * w;
  }
  osm[((size_t)(bn << 2) + 0) * HID + ch] = a0;
  osm[((size_t)(bn << 2) + 1) * HID + ch] = a1;
  osm[((size_t)(bn << 2) + 2) * HID + ch] = a2;
  osm[((size_t)(bn << 2) + 3) * HID + ch] = a3;
}

// ---- Ai ----
template <typename ST>
__global__ __launch_bounds__(256)
void ai_kernel(const ST* __restrict__ q, const float* __restrict__ k,
               float* __restrict__ Ai) {
  const int bn = blockIdx.x;
  const int b = bn >> 6;
  const int wave = threadIdx.x >> 6, lane = threadIdx.x & 63;
  const size_t roff = ((size_t)bn * 64 + wave) * HID;
  float s = 0.f;
#pragma unroll
  for (int it = 0; it < 4; ++it) {
    int d = (lane << 2) + (it << 8);
    float4 a = ld4(&q[roff + d]);
    float4 b4 = *(const float4*)&k[roff + d];
    s += a.x*b4.x + a.y*b4.y + a.z*b4.z + a.w*b4.w;
  }
#pragma unroll
  for (int off = 32; off; off >>= 1) s += __shfl_xor(s, off);
  if (lane == 0) Ai[(bn << 2) + wave] = (wave <= b) ? s : 0.f;
}

// ---- o = q*Sd + (c<=b)*Ai*osm, RMSNorm*g ; in-place over q ----
template <typename ST>
__global__ __launch_bounds__(256)
void o_kernel(ST* __restrict__ q, const float* __restrict__ Sdp,
              const float* __restrict__ osm, const float* __restrict__ Ai,
              const float* __restrict__ g) {
  const int row = blockIdx.x;
  const int b = row >> 12;
  const int l = row & (LL - 1);
  const int n = l >> 6, c = l & 63;
  const int ch = threadIdx.x << 2;
  const size_t ro = (size_t)row * HID;
  float4 qv = ld4(&q[ro + ch]);
  float4 sd = *(const float4*)&Sdp[(size_t)((n << 2) + b) * HID + ch];
  float ox = qv.x*sd.x, oy = qv.y*sd.y, oz = qv.z*sd.z, ow = qv.w*sd.w;
  if (c <= b) {
    int bn = (b << 6) + n;
    float a = Ai[(bn << 2) + c];
    float4 u = *(const float4*)&osm[((size_t)(bn << 2) + c) * HID + ch];
    ox += a * u.x; oy += a * u.y; oz += a * u.z; ow += a * u.w;
  }
  float ss = ox*ox + oy*oy + oz*oz + ow*ow;
#pragma unroll
  for (int off = 32; off; off >>= 1) ss += __shfl_xor(ss, off);
  float scale = 1.f / sqrtf(ss * (1.f / HD) + 1e-5f);
  float4 gv = *(const float4*)&g[ch & (HD - 1)];
  st4(&q[ro + ch], make_float4(ox*scale*gv.x, oy*scale*gv.y, oz*scale*gv.z, ow*scale*gv.w));
}

// ---- final S partials: block = ((bh*4+eq)*ngroups + ng), chunks [ng*npg, +npg) ----
template <typename ST>
__global__ __launch_bounds__(256)
void sfinal_part(const float* __restrict__ k, const ST* __restrict__ v,
                 const float* __restrict__ beta, const float* __restrict__ Tg,
                 const float* __restrict__ Sdp, float* __restrict__ Spart,
                 int ngroups, int npg) {
  __shared__ float Ts[4096];
  __shared__ float va[64][68];
  __shared__ float us[64][68];
  __shared__ float bs[64];
  const int ng = blockIdx.x % ngroups;
  const int be = blockIdx.x / ngroups;
  const int bh = be >> 2, eq = be & 3;
  const int b = bh >> 2, h = bh & 3;
  const int e0 = eq << 6;
  const int tid = threadIdx.x;
  float4 acc[16];
#pragma unroll
  for (int j4 = 0; j4 < 16; ++j4) acc[j4] = make_float4(0.f, 0.f, 0.f, 0.f);
  for (int n = ng * npg; n < ng * npg + npg; ++n) {
    const int bn = (b << 6) + n;
    const size_t base = (size_t)bn * 64 * HID;
    __syncthreads();
#pragma unroll
    for (int ii = 0; ii < 4; ++ii) {
      int off = (tid << 4) + (ii << 2);
      *(float4*)&Ts[off] = *(const float4*)&Tg[(size_t)bn * 4096 + off];
    }
    if (tid < 64) bs[tid] = beta[(((bn << 6) + tid) << 2) + h];
    __syncthreads();
#pragma unroll
    for (int p = 0; p < 16; ++p) {
      int idx = tid + (p << 8);
      int rr = idx >> 6, e = idx & 63;
      int chg = (h << 8) + e0 + e;
      float sdv = Sdp[(size_t)((n << 2) + b) * HID + chg];
      float kj = k[base + (size_t)rr * HID + chg];
      float vj = ldv(&v[base + (size_t)rr * HID + chg]);
      va[rr][e] = vj - bs[rr] * kj * sdv;
    }
    __syncthreads();
#pragma unroll
    for (int p = 0; p < 16; ++p) {
      int idx = tid + (p << 8);
      int c = idx >> 6, e = idx & 63;
      float s = 0.f;
#pragma unroll 16
      for (int j = 0; j < 64; ++j) s += Ts[(c << 6) + j] * va[j][e];
      us[c][e] = s;
    }
    __syncthreads();
    const int chd = (h << 8) + tid;
    for (int c = 0; c < 64; ++c) {
      float kv = k[base + (size_t)c * HID + chd];
#pragma unroll
      for (int j4 = 0; j4 < 16; ++j4) {
        float4 u4 = *(const float4*)&us[c][j4 << 2];
        acc[j4].x += kv*u4.x; acc[j4].y += kv*u4.y;
        acc[j4].z += kv*u4.z; acc[j4].w += kv*u4.w;
      }
    }
  }
  const size_t ob = (size_t)ng * SSIZE + ((size_t)(bh << 8) + tid) * HD + e0;
#pragma unroll
  for (int j4 = 0; j4 < 16; ++j4)
    *(float4*)&Spart[ob + (j4 << 2)] = acc[j4];
}

// ---- reduce partials -> Sout ----
__global__ __launch_bounds__(256)
void sreduce_kernel(const float* __restrict__ Spart, float* __restrict__ Sout,
                    int ngroups) {
  size_t i = ((size_t)blockIdx.x * 256 + threadIdx.x) << 2;
  float4 s = make_float4(0.f, 0.f, 0.f, 0.f);
  for (int g = 0; g < ngroups; ++g) {
    float4 p = *(const float4*)&Spart[(size_t)g * SSIZE + i];
    s.x += p.x; s.y += p.y; s.z += p.z; s.w += p.w;
  }
  *(float4*)&Sout[i] = s;
}

template <typename ST>
static void run_pipeline(const float* x, const float* Wq, const float* Wk,
                         const float* Wv, const float* Wb, const float* cq,
                         const float* ck, const float* cv, const float* g,
                         const float* Wo, float* out, float* Sout, float* kbuf,
                         float* Tg, float* betab, float* Aib, float* Pb,
                         float* Rb, float* Sdp, float* osmb, ST* qbuf, ST* vbuf,
                         int ngroups, hipStream_t stream) {
  dim3 gg(ROWS / 128, HID / 128);
  float* lin = out;   // d_out[0..16M) as scratch until gemm_out
  beta_kernel<<<ROWS / 4, 256, 0, stream>>>(x, Wb, betab);
  gemm128<float><<<gg, 256, 0, stream>>>(x, Wq, lin);
  conv_kernel<0, ST><<<ROWS, 256, 0, stream>>>(lin, cq, betab, qbuf);
  gemm128<float><<<gg, 256, 0, stream>>>(x, Wk, lin);
  conv_kernel<1, float><<<ROWS, 256, 0, stream>>>(lin, ck, betab, kbuf);
  gemm128<float><<<gg, 256, 0, stream>>>(x, Wv, lin);
  conv_kernel<2, ST><<<ROWS, 256, 0, stream>>>(lin, cv, betab, vbuf);
  chunkT_kernel<<<BB * NCH, 256, 0, stream>>>(kbuf, betab, Tg);
  prct_kernel<ST><<<BB * NCH * NH, 256, 0, stream>>>(kbuf, vbuf, betab, Tg, Pb, Rb);
  scan_kernel<<<16, 256, 0, stream>>>(Pb, Rb, Sdp);
  osm_kernel<ST><<<BB * NCH * NH, 256, 0, stream>>>(kbuf, vbuf, betab, Tg, Sdp, osmb);
  ai_kernel<ST><<<BB * NCH, 256, 0, stream>>>(qbuf, kbuf, Aib);
  o_kernel<ST><<<ROWS, 256, 0, stream>>>(qbuf, Sdp, osmb, Aib, g);
  gemm128<ST><<<gg, 256, 0, stream>>>(qbuf, Wo, out);
  // qbuf now free -> reuse as fp32 partial buffer for S
  float* Spart = (float*)qbuf;
  int npg = 64 / ngroups;
  sfinal_part<ST><<<64 * ngroups, 256, 0, stream>>>(kbuf, vbuf, betab, Tg, Sdp,
                                                    Spart, ngroups, npg);
  sreduce_kernel<<<SSIZE / 1024, 256, 0, stream>>>(Spart, Sout, ngroups);
}

extern "C" void kernel_launch(void* const* d_in, const int* in_sizes, int n_in,
                              void* d_out, int out_size, void* d_ws, size_t ws_size,
                              hipStream_t stream) {
  const float* x  = (const float*)d_in[0];
  const float* Wq = (const float*)d_in[1];
  const float* Wk = (const float*)d_in[2];
  const float* Wv = (const float*)d_in[3];
  const float* Wb = (const float*)d_in[4];
  const float* cq = (const float*)d_in[5];
  const float* ck = (const float*)d_in[6];
  const float* cv = (const float*)d_in[7];
  const float* g  = (const float*)d_in[8];
  const float* Wo = (const float*)d_in[9];
  float* out  = (float*)d_out;
  float* Sout = out + (size_t)ROWS * HID;

  const size_t F = (size_t)ROWS * HID;
  char* w = (char*)d_ws;
  float* kbuf  = (float*)w;  w += F * 4;
  float* Tg    = (float*)w;  w += (size_t)BB * NCH * 4096 * 4;
  float* betab = (float*)w;  w += (size_t)ROWS * NH * 4;
  float* Aib   = (float*)w;  w += (size_t)BB * NCH * 4 * 4;
  float* Pb    = (float*)w;  w += (size_t)BB * NCH * HID * 4;
  float* Rb    = (float*)w;  w += (size_t)BB * NCH * HID * 4;
  float* Sdp   = (float*)w;  w += (size_t)BB * NCH * HID * 4;
  float* osmb  = (float*)w;  w += (size_t)BB * NCH * 4 * HID * 4;
  char* qv = w;
  const size_t fixed = (size_t)(qv - (char*)d_ws);
  const size_t needA = fixed + 2 * F * sizeof(float);
  const size_t needB = fixed + 2 * F * sizeof(bf16);

  if (ws_size >= needA) {
    float* qbuf = (float*)qv;
    float* vbuf = (float*)(qv + F * sizeof(float));
    run_pipeline<float>(x, Wq, Wk, Wv, Wb, cq, ck, cv, g, Wo, out, Sout, kbuf,
                        Tg, betab, Aib, Pb, Rb, Sdp, osmb, qbuf, vbuf,
                        16, stream);
  } else if (ws_size >= needB) {
    bf16* qbuf = (bf16*)qv;
    bf16* vbuf = (bf16*)(qv + F * sizeof(bf16));
    run_pipeline<bf16>(x, Wq, Wk, Wv, Wb, cq, ck, cv, g, Wo, out, Sout, kbuf,
                       Tg, betab, Aib, Pb, Rb, Sdp, osmb, qbuf, vbuf,
                       8, stream);
  }
}

// Round 10
// 1331.509 us; speedup vs baseline: 6.3301x; 1.7552x over previous
//
#include <hip/hip_runtime.h>
#include <hip/hip_bf16.h>

#define HID 1024
#define NH 4
#define HD 256
#define NCH 64
#define BB 4
#define LL 4096
#define ROWS (BB*LL)
#define SSIZE (BB*NH*HD*HD)

typedef __hip_bfloat16 bf16;
typedef __attribute__((ext_vector_type(8))) short short8;
typedef __attribute__((ext_vector_type(4))) float f32x4;

struct u16x4 { unsigned short x, y, z, w; };

__device__ __forceinline__ float bfu2f(unsigned short u) {
  return __uint_as_float(((unsigned int)u) << 16);
}
__device__ __forceinline__ unsigned short f2bfu(float f) {
  unsigned int x = __float_as_uint(f);
  return (unsigned short)((x + 0x7FFFu + ((x >> 16) & 1u)) >> 16);
}
__device__ __forceinline__ float ldv(const float* p) { return *p; }
__device__ __forceinline__ float ldv(const bf16* p) { return bfu2f(*(const unsigned short*)p); }
__device__ __forceinline__ float4 ld4(const float* p) { return *(const float4*)p; }
__device__ __forceinline__ float4 ld4(const bf16* p) {
  u16x4 u = *(const u16x4*)p;
  return make_float4(bfu2f(u.x), bfu2f(u.y), bfu2f(u.z), bfu2f(u.w));
}
__device__ __forceinline__ void st4(float* p, float4 v) { *(float4*)p = v; }
__device__ __forceinline__ void st4(bf16* p, float4 v) {
  u16x4 u; u.x = f2bfu(v.x); u.y = f2bfu(v.y); u.z = f2bfu(v.z); u.w = f2bfu(v.w);
  *(u16x4*)p = u;
}

typedef const __attribute__((address_space(1))) unsigned int* gptr_t;
typedef __attribute__((address_space(3))) unsigned int* lptr_t;
__device__ __forceinline__ void gload16(const void* g, void* l) {
  __builtin_amdgcn_global_load_lds((gptr_t)g, (lptr_t)l, 16, 0, 0);
}

// ---------------- beta = sigmoid(x @ Wb) ----------------
__global__ __launch_bounds__(256)
void beta_kernel(const float* __restrict__ x, const float* __restrict__ Wb,
                 float* __restrict__ beta) {
  const int wave = threadIdx.x >> 6, lane = threadIdx.x & 63;
  const int m = (blockIdx.x << 2) + wave;
  const float* xr = x + (size_t)m * HID;
  float a0 = 0.f, a1 = 0.f, a2 = 0.f, a3 = 0.f;
#pragma unroll
  for (int it = 0; it < 16; ++it) {
    int kk = lane + (it << 6);
    float xv = xr[kk];
    float4 w = *(const float4*)&Wb[kk << 2];
    a0 += xv * w.x; a1 += xv * w.y; a2 += xv * w.z; a3 += xv * w.w;
  }
#pragma unroll
  for (int off = 32; off; off >>= 1) {
    a0 += __shfl_xor(a0, off); a1 += __shfl_xor(a1, off);
    a2 += __shfl_xor(a2, off); a3 += __shfl_xor(a3, off);
  }
  if (lane == 0) {
    float4 r;
    r.x = 1.f / (1.f + expf(-a0)); r.y = 1.f / (1.f + expf(-a1));
    r.z = 1.f / (1.f + expf(-a2)); r.w = 1.f / (1.f + expf(-a3));
    *(float4*)&beta[m << 2] = r;
  }
}

// ---- convert x (fp32) -> xb (bf16) ----
__global__ __launch_bounds__(256)
void convX_kernel(const float* __restrict__ x, bf16* __restrict__ xb) {
  size_t i = ((size_t)blockIdx.x * 256 + threadIdx.x) << 2;
  st4(&xb[i], *(const float4*)&x[i]);
}

// ---- convert + transpose weight: Wt[n][k] = bf16(W[k][n]) ----
__global__ __launch_bounds__(256)
void convT_kernel(const float* __restrict__ W, unsigned short* __restrict__ Wt) {
  __shared__ unsigned short t[64][68];
  const int kt = blockIdx.x << 6, nt = blockIdx.y << 6;
  const int tid = threadIdx.x;
#pragma unroll
  for (int i = 0; i < 16; ++i) {
    int idx = tid + (i << 8);
    int r = idx >> 6, c = idx & 63;
    t[r][c] = f2bfu(W[(size_t)(kt + r) * HID + nt + c]);
  }
  __syncthreads();
#pragma unroll
  for (int i = 0; i < 16; ++i) {
    int idx = tid + (i << 8);
    int n = idx >> 6, kk = idx & 63;
    Wt[(size_t)(nt + n) * HID + kt + kk] = t[kk][n];
  }
}

// ---- bf16 MFMA GEMM: C[M][1024] = A[M][1024] @ Bt^T, Bt = [1024 n][1024 k] bf16 ----
// 128x128 tile, 4 waves (2x2 of 64x64), BK=32, global_load_lds staging.
__global__ __launch_bounds__(256)
void mfma_gemm(const unsigned short* __restrict__ A,
               const unsigned short* __restrict__ Bt, float* __restrict__ C) {
  __shared__ unsigned short Asl[128 * 32];
  __shared__ unsigned short Bsl[128 * 32];
  const int tid = threadIdx.x;
  const int wave = tid >> 6, lane = tid & 63;
  const int m0 = blockIdx.x << 7, n0 = blockIdx.y << 7;
  const int wr = wave >> 1, wc = wave & 1;
  f32x4 acc[4][4] = {};
  const int cA = (wave << 6) + lane;       // chunk id, issue 0
  for (int k0 = 0; k0 < HID; k0 += 32) {
#pragma unroll
    for (int i = 0; i < 2; ++i) {
      int c = cA + (i << 8);
      int row = c >> 2, ko = (c & 3) << 3;       // 4x16B chunks per 32-elem row
      gload16(&A[(size_t)(m0 + row) * HID + k0 + ko],
              &Asl[(size_t)((i << 8) + (wave << 6)) * 8]);
      gload16(&Bt[(size_t)(n0 + row) * HID + k0 + ko],
              &Bsl[(size_t)((i << 8) + (wave << 6)) * 8]);
    }
    __syncthreads();
    short8 af[4], bfr[4];
#pragma unroll
    for (int f = 0; f < 4; ++f) {
      int ra = (wr << 6) + (f << 4) + (lane & 15);
      af[f] = *(const short8*)&Asl[ra * 32 + ((lane >> 4) << 3)];
      int rb = (wc << 6) + (f << 4) + (lane & 15);
      bfr[f] = *(const short8*)&Bsl[rb * 32 + ((lane >> 4) << 3)];
    }
#pragma unroll
    for (int i = 0; i < 4; ++i)
#pragma unroll
      for (int j = 0; j < 4; ++j)
        acc[i][j] = __builtin_amdgcn_mfma_f32_16x16x32_bf16(af[i], bfr[j],
                                                            acc[i][j], 0, 0, 0);
    __syncthreads();
  }
#pragma unroll
  for (int i = 0; i < 4; ++i) {
    int r0 = m0 + (wr << 6) + (i << 4) + ((lane >> 4) << 2);
#pragma unroll
    for (int j = 0; j < 4; ++j) {
      int c0 = n0 + (wc << 6) + (j << 4) + (lane & 15);
#pragma unroll
      for (int r = 0; r < 4; ++r)
        C[(size_t)(r0 + r) * HID + c0] = acc[i][j][r];
    }
  }
}

// ---- 128x128 fp32 GEMM (k path), 8x8/thread ----
__global__ __launch_bounds__(256)
void gemm128(const float* __restrict__ A, const float* __restrict__ B,
             float* __restrict__ C) {
  __shared__ float As[16][132];
  __shared__ float Bs[16][128];
  const int m0 = blockIdx.x << 7, n0 = blockIdx.y << 7;
  const int tid = threadIdx.x;
  const int tr = tid >> 4, tc = tid & 15;
  float acc[8][8] = {{0.f}};
  for (int k0 = 0; k0 < HID; k0 += 16) {
#pragma unroll
    for (int it = 0; it < 2; ++it) {
      int idx = tid + (it << 8);
      int r = idx >> 2, c4 = (idx & 3) << 2;
      float4 a = *(const float4*)&A[(size_t)(m0 + r) * HID + k0 + c4];
      As[c4 + 0][r] = a.x; As[c4 + 1][r] = a.y;
      As[c4 + 2][r] = a.z; As[c4 + 3][r] = a.w;
      int r2 = idx >> 5, c42 = (idx & 31) << 2;
      *(float4*)&Bs[r2][c42] = *(const float4*)&B[(size_t)(k0 + r2) * HID + n0 + c42];
    }
    __syncthreads();
#pragma unroll
    for (int kk = 0; kk < 16; ++kk) {
      float4 a0 = *(const float4*)&As[kk][tr << 2];
      float4 a1 = *(const float4*)&As[kk][64 + (tr << 2)];
      float4 b0 = *(const float4*)&Bs[kk][tc << 2];
      float4 b1 = *(const float4*)&Bs[kk][64 + (tc << 2)];
      float av[8] = {a0.x, a0.y, a0.z, a0.w, a1.x, a1.y, a1.z, a1.w};
      float bv[8] = {b0.x, b0.y, b0.z, b0.w, b1.x, b1.y, b1.z, b1.w};
#pragma unroll
      for (int i = 0; i < 8; ++i)
#pragma unroll
        for (int j = 0; j < 8; ++j) acc[i][j] += av[i] * bv[j];
    }
    __syncthreads();
  }
#pragma unroll
  for (int half = 0; half < 2; ++half)
#pragma unroll
    for (int i = 0; i < 4; ++i) {
      int row = m0 + (half << 6) + (tr << 2) + i;
      float* cr = &C[(size_t)row * HID + n0];
      *(float4*)&cr[tc << 2] =
          make_float4(acc[(half<<2)+i][0], acc[(half<<2)+i][1],
                      acc[(half<<2)+i][2], acc[(half<<2)+i][3]);
      *(float4*)&cr[64 + (tc << 2)] =
          make_float4(acc[(half<<2)+i][4], acc[(half<<2)+i][5],
                      acc[(half<<2)+i][6], acc[(half<<2)+i][7]);
    }
}

// ------- causal depthwise conv(K=4) + SiLU (+L2 norm / +beta) -------
template <int MODE, typename ST>
__global__ __launch_bounds__(256)
void conv_kernel(const float* __restrict__ lin, const float* __restrict__ w,
                 const float* __restrict__ beta, ST* __restrict__ out) {
  const int row = blockIdx.x;
  const int l = row & (LL - 1);
  const int tid = threadIdx.x;
  const int ch = tid << 2;
  float wv[4][4];
#pragma unroll
  for (int j = 0; j < 4; ++j) {
    float4 t4 = *(const float4*)&w[(ch + j) << 2];
    wv[j][0] = t4.x; wv[j][1] = t4.y; wv[j][2] = t4.z; wv[j][3] = t4.w;
  }
  float y[4] = {0.f, 0.f, 0.f, 0.f};
#pragma unroll
  for (int t = 0; t < 4; ++t) {
    if (l - 3 + t >= 0) {
      float4 xv = *(const float4*)&lin[(size_t)(row - 3 + t) * HID + ch];
      y[0] += xv.x * wv[0][t]; y[1] += xv.y * wv[1][t];
      y[2] += xv.z * wv[2][t]; y[3] += xv.w * wv[3][t];
    }
  }
#pragma unroll
  for (int j = 0; j < 4; ++j) y[j] = y[j] / (1.f + expf(-y[j]));
  float scale;
  if (MODE < 2) {
    float ss = y[0]*y[0] + y[1]*y[1] + y[2]*y[2] + y[3]*y[3];
#pragma unroll
    for (int off = 32; off; off >>= 1) ss += __shfl_xor(ss, off);
    scale = 1.f / sqrtf(ss);
  } else {
    scale = beta[(row << 2) + (tid >> 6)];
  }
  st4(&out[(size_t)row * HID + ch],
      make_float4(y[0]*scale, y[1]*scale, y[2]*scale, y[3]*scale));
}

// ---- per-(b,n): T recurrence (fp32), store T ----
__global__ __launch_bounds__(256)
void chunkT_kernel(const float* __restrict__ k, const float* __restrict__ beta,
                   float* __restrict__ Tg) {
  __shared__ float T[64][68];
  __shared__ float S1[64][68];
  __shared__ float S2[64][68];
  __shared__ float row_s[64];
  const int bn = blockIdx.x;
  const size_t base = (size_t)bn * 64 * HID;
  const int tid = threadIdx.x;
  const int tr = tid >> 4, tc = tid & 15;
  float acc[4][4] = {{0.f}};
  for (int d0 = 0; d0 < HID; d0 += 64) {
    const int h = d0 >> 8;
#pragma unroll
    for (int p = 0; p < 4; ++p) {
      int rr = (tid >> 4) + (p << 4);
      int c4 = (tid & 15) << 2;
      float4 a = *(const float4*)&k[base + (size_t)rr * HID + d0 + c4];
      float bta = beta[(((bn << 6) + rr) << 2) + h];
      S2[c4 + 0][rr] = a.x; S2[c4 + 1][rr] = a.y;
      S2[c4 + 2][rr] = a.z; S2[c4 + 3][rr] = a.w;
      S1[c4 + 0][rr] = a.x * bta; S1[c4 + 1][rr] = a.y * bta;
      S1[c4 + 2][rr] = a.z * bta; S1[c4 + 3][rr] = a.w * bta;
    }
    __syncthreads();
#pragma unroll
    for (int dd = 0; dd < 64; ++dd) {
      float4 a = *(const float4*)&S1[dd][tr << 2];
      float4 b = *(const float4*)&S2[dd][tc << 2];
      acc[0][0] += a.x*b.x; acc[0][1] += a.x*b.y; acc[0][2] += a.x*b.z; acc[0][3] += a.x*b.w;
      acc[1][0] += a.y*b.x; acc[1][1] += a.y*b.y; acc[1][2] += a.y*b.z; acc[1][3] += a.y*b.w;
      acc[2][0] += a.z*b.x; acc[2][1] += a.z*b.y; acc[2][2] += a.z*b.z; acc[2][3] += a.z*b.w;
      acc[3][0] += a.w*b.x; acc[3][1] += a.w*b.y; acc[3][2] += a.w*b.z; acc[3][3] += a.w*b.w;
    }
    __syncthreads();
  }
#pragma unroll
  for (int i = 0; i < 4; ++i)
#pragma unroll
    for (int j = 0; j < 4; ++j) {
      int ri = (tr << 2) + i, cj = (tc << 2) + j;
      T[ri][cj] = (ri == cj) ? 1.f : (ri > cj ? -acc[i][j] : 0.f);
    }
  __syncthreads();
  for (int i = 1; i < 64; ++i) {
    if (tid < 64) row_s[tid] = T[i][tid];
    __syncthreads();
    if (tid < 64) {
      float a = 0.f;
#pragma unroll 8
      for (int j = 0; j < 64; ++j) a += row_s[j] * T[j][tid];
      if (tid < i) T[i][tid] = row_s[tid] + a;
    }
    __syncthreads();
  }
#pragma unroll
  for (int ii = 0; ii < 4; ++ii) {
    int off = (tid << 4) + (ii << 2);
    int c = off >> 6, j = off & 63;
    *(float4*)&Tg[(size_t)bn * 4096 + off] = *(const float4*)&T[c][j];
  }
}

// ---- P,R via ct[j,ch] = sum_c T[c,j]*k[c,ch] ----
template <typename ST>
__global__ __launch_bounds__(256)
void prct_kernel(const float* __restrict__ k, const ST* __restrict__ v,
                 const float* __restrict__ beta, const float* __restrict__ Tg,
                 float* __restrict__ P, float* __restrict__ R) {
  __shared__ float Ts[4096];
  __shared__ float bs[64];
  const int bn = blockIdx.x >> 2, h = blockIdx.x & 3;
  const int tid = threadIdx.x;
#pragma unroll
  for (int ii = 0; ii < 4; ++ii) {
    int off = (tid << 4) + (ii << 2);
    *(float4*)&Ts[off] = *(const float4*)&Tg[(size_t)bn * 4096 + off];
  }
  if (tid < 64) bs[tid] = beta[(((bn << 6) + tid) << 2) + h];
  __syncthreads();
  const int ch = (h << 8) + tid;
  const size_t base = (size_t)bn * 64 * HID;
  float ct[64];
#pragma unroll
  for (int j = 0; j < 64; ++j) ct[j] = 0.f;
  for (int c = 0; c < 64; ++c) {
    float kc = k[base + (size_t)c * HID + ch];
#pragma unroll
    for (int j = 0; j < 64; ++j) ct[j] += Ts[(c << 6) + j] * kc;
  }
  float p = 0.f, r = 0.f;
#pragma unroll
  for (int j = 0; j < 64; ++j) {
    float kj = k[base + (size_t)j * HID + ch];
    float vj = ldv(&v[base + (size_t)j * HID + ch]);
    p += bs[j] * kj * ct[j];
    r += vj * ct[j];
  }
  P[(size_t)bn * HID + ch] = p;
  R[(size_t)bn * HID + ch] = r;
}

// ---- diagonal scan ----
__global__ __launch_bounds__(256)
void scan_kernel(const float* __restrict__ P, const float* __restrict__ R,
                 float* __restrict__ Sdp) {
  const int b = blockIdx.x >> 2;
  const int ch = ((blockIdx.x & 3) << 8) + threadIdx.x;
  float S = 0.f;
  for (int n = 0; n < 64; ++n) {
    Sdp[(size_t)((n << 2) + b) * HID + ch] = S;
    float p = P[(size_t)((b << 6) + n) * HID + ch];
    float r = R[(size_t)((b << 6) + n) * HID + ch];
    S = S * (1.f - p) + r;
  }
}

// ---- osm rows c=0..3 ----
template <typename ST>
__global__ __launch_bounds__(256)
void osm_kernel(const float* __restrict__ k, const ST* __restrict__ v,
                const float* __restrict__ beta, const float* __restrict__ Tg,
                const float* __restrict__ Sdp, float* __restrict__ osm) {
  __shared__ float Ts4[4][64];
  __shared__ float bs[64];
  const int bn = blockIdx.x >> 2, h = blockIdx.x & 3;
  const int b = bn >> 6, n = bn & 63;
  const int tid = threadIdx.x;
  Ts4[tid >> 6][tid & 63] = Tg[(size_t)bn * 4096 + tid];
  if (tid < 64) bs[tid] = beta[(((bn << 6) + tid) << 2) + h];
  __syncthreads();
  const int ch = (h << 8) + tid;
  const size_t base = (size_t)bn * 64 * HID;
  float sd = Sdp[(size_t)((n << 2) + b) * HID + ch];
  float a0 = 0.f, a1 = 0.f, a2 = 0.f, a3 = 0.f;
  for (int j = 0; j < 64; ++j) {
    float kj = k[base + (size_t)j * HID + ch];
    float vj = ldv(&v[base + (size_t)j * HID + ch]);
    float w = vj - bs[j] * kj * sd;
    a0 += Ts4[0][j] * w; a1 += Ts4[1][j] * w;
    a2 += Ts4[2][j] * w; a3 += Ts4[3][j] * w;
  }
  osm[((size_t)(bn << 2) + 0) * HID + ch] = a0;
  osm[((size_t)(bn << 2) + 1) * HID + ch] = a1;
  osm[((size_t)(bn << 2) + 2) * HID + ch] = a2;
  osm[((size_t)(bn << 2) + 3) * HID + ch] = a3;
}

// ---- Ai ----
template <typename ST>
__global__ __launch_bounds__(256)
void ai_kernel(const ST* __restrict__ q, const float* __restrict__ k,
               float* __restrict__ Ai) {
  const int bn = blockIdx.x;
  const int b = bn >> 6;
  const int wave = threadIdx.x >> 6, lane = threadIdx.x & 63;
  const size_t roff = ((size_t)bn * 64 + wave) * HID;
  float s = 0.f;
#pragma unroll
  for (int it = 0; it < 4; ++it) {
    int d = (lane << 2) + (it << 8);
    float4 a = ld4(&q[roff + d]);
    float4 b4 = *(const float4*)&k[roff + d];
    s += a.x*b4.x + a.y*b4.y + a.z*b4.z + a.w*b4.w;
  }
#pragma unroll
  for (int off = 32; off; off >>= 1) s += __shfl_xor(s, off);
  if (lane == 0) Ai[(bn << 2) + wave] = (wave <= b) ? s : 0.f;
}

// ---- o = q*Sd + (c<=b)*Ai*osm, RMSNorm*g ; in-place over q ----
template <typename ST>
__global__ __launch_bounds__(256)
void o_kernel(ST* __restrict__ q, const float* __restrict__ Sdp,
              const float* __restrict__ osm, const float* __restrict__ Ai,
              const float* __restrict__ g) {
  const int row = blockIdx.x;
  const int b = row >> 12;
  const int l = row & (LL - 1);
  const int n = l >> 6, c = l & 63;
  const int ch = threadIdx.x << 2;
  const size_t ro = (size_t)row * HID;
  float4 qv = ld4(&q[ro + ch]);
  float4 sd = *(const float4*)&Sdp[(size_t)((n << 2) + b) * HID + ch];
  float ox = qv.x*sd.x, oy = qv.y*sd.y, oz = qv.z*sd.z, ow = qv.w*sd.w;
  if (c <= b) {
    int bn = (b << 6) + n;
    float a = Ai[(bn << 2) + c];
    float4 u = *(const float4*)&osm[((size_t)(bn << 2) + c) * HID + ch];
    ox += a * u.x; oy += a * u.y; oz += a * u.z; ow += a * u.w;
  }
  float ss = ox*ox + oy*oy + oz*oz + ow*ow;
#pragma unroll
  for (int off = 32; off; off >>= 1) ss += __shfl_xor(ss, off);
  float scale = 1.f / sqrtf(ss * (1.f / HD) + 1e-5f);
  float4 gv = *(const float4*)&g[ch & (HD - 1)];
  st4(&q[ro + ch], make_float4(ox*scale*gv.x, oy*scale*gv.y, oz*scale*gv.z, ow*scale*gv.w));
}

// ---- final S partials ----
template <typename ST>
__global__ __launch_bounds__(256)
void sfinal_part(const float* __restrict__ k, const ST* __restrict__ v,
                 const float* __restrict__ beta, const float* __restrict__ Tg,
                 const float* __restrict__ Sdp, float* __restrict__ Spart,
                 int ngroups, int npg) {
  __shared__ float Ts[4096];
  __shared__ float va[64][68];
  __shared__ float us[64][68];
  __shared__ float bs[64];
  const int ng = blockIdx.x % ngroups;
  const int be = blockIdx.x / ngroups;
  const int bh = be >> 2, eq = be & 3;
  const int b = bh >> 2, h = bh & 3;
  const int e0 = eq << 6;
  const int tid = threadIdx.x;
  float4 acc[16];
#pragma unroll
  for (int j4 = 0; j4 < 16; ++j4) acc[j4] = make_float4(0.f, 0.f, 0.f, 0.f);
  for (int n = ng * npg; n < ng * npg + npg; ++n) {
    const int bn = (b << 6) + n;
    const size_t base = (size_t)bn * 64 * HID;
    __syncthreads();
#pragma unroll
    for (int ii = 0; ii < 4; ++ii) {
      int off = (tid << 4) + (ii << 2);
      *(float4*)&Ts[off] = *(const float4*)&Tg[(size_t)bn * 4096 + off];
    }
    if (tid < 64) bs[tid] = beta[(((bn << 6) + tid) << 2) + h];
    __syncthreads();
#pragma unroll
    for (int p = 0; p < 16; ++p) {
      int idx = tid + (p << 8);
      int rr = idx >> 6, e = idx & 63;
      int chg = (h << 8) + e0 + e;
      float sdv = Sdp[(size_t)((n << 2) + b) * HID + chg];
      float kj = k[base + (size_t)rr * HID + chg];
      float vj = ldv(&v[base + (size_t)rr * HID + chg]);
      va[rr][e] = vj - bs[rr] * kj * sdv;
    }
    __syncthreads();
#pragma unroll
    for (int p = 0; p < 16; ++p) {
      int idx = tid + (p << 8);
      int c = idx >> 6, e = idx & 63;
      float s = 0.f;
#pragma unroll 16
      for (int j = 0; j < 64; ++j) s += Ts[(c << 6) + j] * va[j][e];
      us[c][e] = s;
    }
    __syncthreads();
    const int chd = (h << 8) + tid;
    for (int c = 0; c < 64; ++c) {
      float kv = k[base + (size_t)c * HID + chd];
#pragma unroll
      for (int j4 = 0; j4 < 16; ++j4) {
        float4 u4 = *(const float4*)&us[c][j4 << 2];
        acc[j4].x += kv*u4.x; acc[j4].y += kv*u4.y;
        acc[j4].z += kv*u4.z; acc[j4].w += kv*u4.w;
      }
    }
  }
  const size_t ob = (size_t)ng * SSIZE + ((size_t)(bh << 8) + tid) * HD + e0;
#pragma unroll
  for (int j4 = 0; j4 < 16; ++j4)
    *(float4*)&Spart[ob + (j4 << 2)] = acc[j4];
}

// ---- reduce partials -> Sout ----
__global__ __launch_bounds__(256)
void sreduce_kernel(const float* __restrict__ Spart, float* __restrict__ Sout,
                    int ngroups) {
  size_t i = ((size_t)blockIdx.x * 256 + threadIdx.x) << 2;
  float4 s = make_float4(0.f, 0.f, 0.f, 0.f);
  for (int g = 0; g < ngroups; ++g) {
    float4 p = *(const float4*)&Spart[(size_t)g * SSIZE + i];
    s.x += p.x; s.y += p.y; s.z += p.z; s.w += p.w;
  }
  *(float4*)&Sout[i] = s;
}

extern "C" void kernel_launch(void* const* d_in, const int* in_sizes, int n_in,
                              void* d_out, int out_size, void* d_ws, size_t ws_size,
                              hipStream_t stream) {
  const float* x  = (const float*)d_in[0];
  const float* Wq = (const float*)d_in[1];
  const float* Wk = (const float*)d_in[2];
  const float* Wv = (const float*)d_in[3];
  const float* Wb = (const float*)d_in[4];
  const float* cq = (const float*)d_in[5];
  const float* ck = (const float*)d_in[6];
  const float* cv = (const float*)d_in[7];
  const float* g  = (const float*)d_in[8];
  const float* Wo = (const float*)d_in[9];
  float* out  = (float*)d_out;
  float* Sout = out + (size_t)ROWS * HID;

  const size_t F = (size_t)ROWS * HID;
  char* w = (char*)d_ws;
  float* kbuf  = (float*)w;  w += F * 4;
  bf16*  xb    = (bf16*)w;   w += F * 2;   // also Spart base (with qbuf) later
  bf16*  qbuf  = (bf16*)w;   w += F * 2;
  bf16*  vbuf  = (bf16*)w;   w += F * 2;
  unsigned short* Wqt = (unsigned short*)w; w += (size_t)HID * HID * 2;
  unsigned short* Wvt = (unsigned short*)w; w += (size_t)HID * HID * 2;
  unsigned short* Wot = (unsigned short*)w; w += (size_t)HID * HID * 2;
  float* Tg    = (float*)w;  w += (size_t)BB * NCH * 4096 * 4;
  float* betab = (float*)w;  w += (size_t)ROWS * NH * 4;
  float* Aib   = (float*)w;  w += (size_t)BB * NCH * 4 * 4;
  float* Pb    = (float*)w;  w += (size_t)BB * NCH * HID * 4;
  float* Rb    = (float*)w;  w += (size_t)BB * NCH * HID * 4;
  float* Sdp   = (float*)w;  w += (size_t)BB * NCH * HID * 4;
  float* osmb  = (float*)w;  w += (size_t)BB * NCH * 4 * HID * 4;
  const size_t need = (size_t)(w - (char*)d_ws);
  if (ws_size < need) return;

  dim3 gg(ROWS / 128, HID / 128);
  dim3 gt(16, 16);
  float* lin = out;   // d_out[0..16M) as scratch until final GEMM

  convX_kernel<<<F / 1024, 256, 0, stream>>>(x, xb);
  convT_kernel<<<gt, 256, 0, stream>>>(Wq, Wqt);
  convT_kernel<<<gt, 256, 0, stream>>>(Wv, Wvt);
  convT_kernel<<<gt, 256, 0, stream>>>(Wo, Wot);
  beta_kernel<<<ROWS / 4, 256, 0, stream>>>(x, Wb, betab);

  mfma_gemm<<<gg, 256, 0, stream>>>((const unsigned short*)xb, Wqt, lin);
  conv_kernel<0, bf16><<<ROWS, 256, 0, stream>>>(lin, cq, betab, qbuf);
  gemm128<<<gg, 256, 0, stream>>>(x, Wk, lin);
  conv_kernel<1, float><<<ROWS, 256, 0, stream>>>(lin, ck, betab, kbuf);
  mfma_gemm<<<gg, 256, 0, stream>>>((const unsigned short*)xb, Wvt, lin);
  conv_kernel<2, bf16><<<ROWS, 256, 0, stream>>>(lin, cv, betab, vbuf);

  chunkT_kernel<<<BB * NCH, 256, 0, stream>>>(kbuf, betab, Tg);
  prct_kernel<bf16><<<BB * NCH * NH, 256, 0, stream>>>(kbuf, vbuf, betab, Tg, Pb, Rb);
  scan_kernel<<<16, 256, 0, stream>>>(Pb, Rb, Sdp);
  osm_kernel<bf16><<<BB * NCH * NH, 256, 0, stream>>>(kbuf, vbuf, betab, Tg, Sdp, osmb);
  ai_kernel<bf16><<<BB * NCH, 256, 0, stream>>>(qbuf, kbuf, Aib);
  o_kernel<bf16><<<ROWS, 256, 0, stream>>>(qbuf, Sdp, osmb, Aib, g);
  mfma_gemm<<<gg, 256, 0, stream>>>((const unsigned short*)qbuf, Wot, out);

  // xb+qbuf (64MB) now dead -> 16-group fp32 partials for S
  float* Spart = (float*)xb;
  const int ngroups = 16, npg = 64 / ngroups;
  sfinal_part<bf16><<<64 * ngroups, 256, 0, stream>>>(kbuf, vbuf, betab, Tg,
                                                      Sdp, Spart, ngroups, npg);
  sreduce_kernel<<<SSIZE / 1024, 256, 0, stream>>>(Spart, Sout, ngroups);
}

// Round 11
// 1074.345 us; speedup vs baseline: 7.8453x; 1.2394x over previous
//
#include <hip/hip_runtime.h>
#include <hip/hip_bf16.h>

#define HID 1024
#define NH 4
#define HD 256
#define NCH 64
#define BB 4
#define LL 4096
#define ROWS (BB*LL)
#define SSIZE (BB*NH*HD*HD)

typedef __hip_bfloat16 bf16;
typedef __attribute__((ext_vector_type(8))) short short8;
typedef __attribute__((ext_vector_type(4))) float f32x4;

struct u16x4 { unsigned short x, y, z, w; };

__device__ __forceinline__ float bfu2f(unsigned short u) {
  return __uint_as_float(((unsigned int)u) << 16);
}
__device__ __forceinline__ unsigned short f2bfu(float f) {
  unsigned int x = __float_as_uint(f);
  return (unsigned short)((x + 0x7FFFu + ((x >> 16) & 1u)) >> 16);
}
__device__ __forceinline__ float ldv(const float* p) { return *p; }
__device__ __forceinline__ float ldv(const bf16* p) { return bfu2f(*(const unsigned short*)p); }
__device__ __forceinline__ float4 ld4(const float* p) { return *(const float4*)p; }
__device__ __forceinline__ float4 ld4(const bf16* p) {
  u16x4 u = *(const u16x4*)p;
  return make_float4(bfu2f(u.x), bfu2f(u.y), bfu2f(u.z), bfu2f(u.w));
}
__device__ __forceinline__ void st4(float* p, float4 v) { *(float4*)p = v; }
__device__ __forceinline__ void st4(bf16* p, float4 v) {
  u16x4 u; u.x = f2bfu(v.x); u.y = f2bfu(v.y); u.z = f2bfu(v.z); u.w = f2bfu(v.w);
  *(u16x4*)p = u;
}

typedef const __attribute__((address_space(1))) unsigned int* gptr_t;
typedef __attribute__((address_space(3))) unsigned int* lptr_t;
__device__ __forceinline__ void gload16(const void* g, void* l) {
  __builtin_amdgcn_global_load_lds((gptr_t)g, (lptr_t)l, 16, 0, 0);
}

// ---------------- beta = sigmoid(x @ Wb) ----------------
__global__ __launch_bounds__(256)
void beta_kernel(const float* __restrict__ x, const float* __restrict__ Wb,
                 float* __restrict__ beta) {
  const int wave = threadIdx.x >> 6, lane = threadIdx.x & 63;
  const int m = (blockIdx.x << 2) + wave;
  const float* xr = x + (size_t)m * HID;
  float a0 = 0.f, a1 = 0.f, a2 = 0.f, a3 = 0.f;
#pragma unroll
  for (int it = 0; it < 16; ++it) {
    int kk = lane + (it << 6);
    float xv = xr[kk];
    float4 w = *(const float4*)&Wb[kk << 2];
    a0 += xv * w.x; a1 += xv * w.y; a2 += xv * w.z; a3 += xv * w.w;
  }
#pragma unroll
  for (int off = 32; off; off >>= 1) {
    a0 += __shfl_xor(a0, off); a1 += __shfl_xor(a1, off);
    a2 += __shfl_xor(a2, off); a3 += __shfl_xor(a3, off);
  }
  if (lane == 0) {
    float4 r;
    r.x = 1.f / (1.f + expf(-a0)); r.y = 1.f / (1.f + expf(-a1));
    r.z = 1.f / (1.f + expf(-a2)); r.w = 1.f / (1.f + expf(-a3));
    *(float4*)&beta[m << 2] = r;
  }
}

// ---- convert x -> hi (bf16) + lo (bf16 of residual) ----
__global__ __launch_bounds__(256)
void convX2_kernel(const float* __restrict__ x, bf16* __restrict__ hi,
                   bf16* __restrict__ lo) {
  size_t i = ((size_t)blockIdx.x * 256 + threadIdx.x) << 2;
  float4 v = *(const float4*)&x[i];
  u16x4 h; h.x = f2bfu(v.x); h.y = f2bfu(v.y); h.z = f2bfu(v.z); h.w = f2bfu(v.w);
  *(u16x4*)&hi[i] = h;
  u16x4 l;
  l.x = f2bfu(v.x - bfu2f(h.x)); l.y = f2bfu(v.y - bfu2f(h.y));
  l.z = f2bfu(v.z - bfu2f(h.z)); l.w = f2bfu(v.w - bfu2f(h.w));
  *(u16x4*)&lo[i] = l;
}

// ---- convert + transpose weight: Wt[n][k] = bf16(W[k][n]) ----
__global__ __launch_bounds__(256)
void convT_kernel(const float* __restrict__ W, unsigned short* __restrict__ Wt) {
  __shared__ unsigned short t[64][68];
  const int kt = blockIdx.x << 6, nt = blockIdx.y << 6;
  const int tid = threadIdx.x;
#pragma unroll
  for (int i = 0; i < 16; ++i) {
    int idx = tid + (i << 8);
    int r = idx >> 6, c = idx & 63;
    t[r][c] = f2bfu(W[(size_t)(kt + r) * HID + nt + c]);
  }
  __syncthreads();
#pragma unroll
  for (int i = 0; i < 16; ++i) {
    int idx = tid + (i << 8);
    int n = idx >> 6, kk = idx & 63;
    Wt[(size_t)(nt + n) * HID + kt + kk] = t[kk][n];
  }
}

// ---- convert + transpose weight into hi/lo bf16 pair ----
__global__ __launch_bounds__(256)
void convT2_kernel(const float* __restrict__ W, unsigned short* __restrict__ Wht,
                   unsigned short* __restrict__ Wlt) {
  __shared__ float t[64][65];
  const int kt = blockIdx.x << 6, nt = blockIdx.y << 6;
  const int tid = threadIdx.x;
#pragma unroll
  for (int i = 0; i < 16; ++i) {
    int idx = tid + (i << 8);
    int r = idx >> 6, c = idx & 63;
    t[r][c] = W[(size_t)(kt + r) * HID + nt + c];
  }
  __syncthreads();
#pragma unroll
  for (int i = 0; i < 16; ++i) {
    int idx = tid + (i << 8);
    int n = idx >> 6, kk = idx & 63;
    float v = t[kk][n];
    unsigned short h = f2bfu(v);
    Wht[(size_t)(nt + n) * HID + kt + kk] = h;
    Wlt[(size_t)(nt + n) * HID + kt + kk] = f2bfu(v - bfu2f(h));
  }
}

// ---- bf16 MFMA GEMM: C = A @ Bt^T (Bt pre-transposed bf16) ----
__global__ __launch_bounds__(256)
void mfma_gemm(const unsigned short* __restrict__ A,
               const unsigned short* __restrict__ Bt, float* __restrict__ C) {
  __shared__ unsigned short Asl[128 * 32];
  __shared__ unsigned short Bsl[128 * 32];
  const int tid = threadIdx.x;
  const int wave = tid >> 6, lane = tid & 63;
  const int m0 = blockIdx.x << 7, n0 = blockIdx.y << 7;
  const int wr = wave >> 1, wc = wave & 1;
  f32x4 acc[4][4] = {};
  const int cA = (wave << 6) + lane;
  for (int k0 = 0; k0 < HID; k0 += 32) {
#pragma unroll
    for (int i = 0; i < 2; ++i) {
      int c = cA + (i << 8);
      int row = c >> 2, ko = (c & 3) << 3;
      gload16(&A[(size_t)(m0 + row) * HID + k0 + ko],
              &Asl[(size_t)((i << 8) + (wave << 6)) * 8]);
      gload16(&Bt[(size_t)(n0 + row) * HID + k0 + ko],
              &Bsl[(size_t)((i << 8) + (wave << 6)) * 8]);
    }
    __syncthreads();
    short8 af[4], bfr[4];
#pragma unroll
    for (int f = 0; f < 4; ++f) {
      int ra = (wr << 6) + (f << 4) + (lane & 15);
      af[f] = *(const short8*)&Asl[ra * 32 + ((lane >> 4) << 3)];
      int rb = (wc << 6) + (f << 4) + (lane & 15);
      bfr[f] = *(const short8*)&Bsl[rb * 32 + ((lane >> 4) << 3)];
    }
#pragma unroll
    for (int i = 0; i < 4; ++i)
#pragma unroll
      for (int j = 0; j < 4; ++j)
        acc[i][j] = __builtin_amdgcn_mfma_f32_16x16x32_bf16(af[i], bfr[j],
                                                            acc[i][j], 0, 0, 0);
    __syncthreads();
  }
#pragma unroll
  for (int i = 0; i < 4; ++i) {
    int r0 = m0 + (wr << 6) + (i << 4) + ((lane >> 4) << 2);
#pragma unroll
    for (int j = 0; j < 4; ++j) {
      int c0 = n0 + (wc << 6) + (j << 4) + (lane & 15);
#pragma unroll
      for (int r = 0; r < 4; ++r)
        C[(size_t)(r0 + r) * HID + c0] = acc[i][j][r];
    }
  }
}

// ---- split-bf16 MFMA GEMM: C = (Ah+Al) @ (Bh+Bl)^T, dropping Al*Bl ----
__global__ __launch_bounds__(256)
void mfma_gemm3(const unsigned short* __restrict__ Ah_,
                const unsigned short* __restrict__ Al_,
                const unsigned short* __restrict__ Bh_,
                const unsigned short* __restrict__ Bl_,
                float* __restrict__ C) {
  __shared__ unsigned short Ah[128 * 32];
  __shared__ unsigned short Al[128 * 32];
  __shared__ unsigned short Bh[128 * 32];
  __shared__ unsigned short Bl[128 * 32];
  const int tid = threadIdx.x;
  const int wave = tid >> 6, lane = tid & 63;
  const int m0 = blockIdx.x << 7, n0 = blockIdx.y << 7;
  const int wr = wave >> 1, wc = wave & 1;
  f32x4 acc[4][4] = {};
  const int cA = (wave << 6) + lane;
  for (int k0 = 0; k0 < HID; k0 += 32) {
#pragma unroll
    for (int i = 0; i < 2; ++i) {
      int c = cA + (i << 8);
      int row = c >> 2, ko = (c & 3) << 3;
      size_t ga = (size_t)(m0 + row) * HID + k0 + ko;
      size_t gb = (size_t)(n0 + row) * HID + k0 + ko;
      size_t ldst = (size_t)((i << 8) + (wave << 6)) * 8;
      gload16(&Ah_[ga], &Ah[ldst]);
      gload16(&Al_[ga], &Al[ldst]);
      gload16(&Bh_[gb], &Bh[ldst]);
      gload16(&Bl_[gb], &Bl[ldst]);
    }
    __syncthreads();
    short8 ah[4], al[4], bh[4], bl[4];
#pragma unroll
    for (int f = 0; f < 4; ++f) {
      int ra = ((wr << 6) + (f << 4) + (lane & 15)) * 32 + ((lane >> 4) << 3);
      ah[f] = *(const short8*)&Ah[ra];
      al[f] = *(const short8*)&Al[ra];
      int rb = ((wc << 6) + (f << 4) + (lane & 15)) * 32 + ((lane >> 4) << 3);
      bh[f] = *(const short8*)&Bh[rb];
      bl[f] = *(const short8*)&Bl[rb];
    }
#pragma unroll
    for (int i = 0; i < 4; ++i)
#pragma unroll
      for (int j = 0; j < 4; ++j) {
        f32x4 a = acc[i][j];
        a = __builtin_amdgcn_mfma_f32_16x16x32_bf16(al[i], bh[j], a, 0, 0, 0);
        a = __builtin_amdgcn_mfma_f32_16x16x32_bf16(ah[i], bl[j], a, 0, 0, 0);
        a = __builtin_amdgcn_mfma_f32_16x16x32_bf16(ah[i], bh[j], a, 0, 0, 0);
        acc[i][j] = a;
      }
    __syncthreads();
  }
#pragma unroll
  for (int i = 0; i < 4; ++i) {
    int r0 = m0 + (wr << 6) + (i << 4) + ((lane >> 4) << 2);
#pragma unroll
    for (int j = 0; j < 4; ++j) {
      int c0 = n0 + (wc << 6) + (j << 4) + (lane & 15);
#pragma unroll
      for (int r = 0; r < 4; ++r)
        C[(size_t)(r0 + r) * HID + c0] = acc[i][j][r];
    }
  }
}

// ------- causal depthwise conv(K=4) + SiLU (+L2 norm / +beta) -------
template <int MODE, typename ST>
__global__ __launch_bounds__(256)
void conv_kernel(const float* __restrict__ lin, const float* __restrict__ w,
                 const float* __restrict__ beta, ST* __restrict__ out) {
  const int row = blockIdx.x;
  const int l = row & (LL - 1);
  const int tid = threadIdx.x;
  const int ch = tid << 2;
  float wv[4][4];
#pragma unroll
  for (int j = 0; j < 4; ++j) {
    float4 t4 = *(const float4*)&w[(ch + j) << 2];
    wv[j][0] = t4.x; wv[j][1] = t4.y; wv[j][2] = t4.z; wv[j][3] = t4.w;
  }
  float y[4] = {0.f, 0.f, 0.f, 0.f};
#pragma unroll
  for (int t = 0; t < 4; ++t) {
    if (l - 3 + t >= 0) {
      float4 xv = *(const float4*)&lin[(size_t)(row - 3 + t) * HID + ch];
      y[0] += xv.x * wv[0][t]; y[1] += xv.y * wv[1][t];
      y[2] += xv.z * wv[2][t]; y[3] += xv.w * wv[3][t];
    }
  }
#pragma unroll
  for (int j = 0; j < 4; ++j) y[j] = y[j] / (1.f + expf(-y[j]));
  float scale;
  if (MODE < 2) {
    float ss = y[0]*y[0] + y[1]*y[1] + y[2]*y[2] + y[3]*y[3];
#pragma unroll
    for (int off = 32; off; off >>= 1) ss += __shfl_xor(ss, off);
    scale = 1.f / sqrtf(ss);
  } else {
    scale = beta[(row << 2) + (tid >> 6)];
  }
  st4(&out[(size_t)row * HID + ch],
      make_float4(y[0]*scale, y[1]*scale, y[2]*scale, y[3]*scale));
}

// ---- per-(b,n): T recurrence (fp32), store T ----
__global__ __launch_bounds__(256)
void chunkT_kernel(const float* __restrict__ k, const float* __restrict__ beta,
                   float* __restrict__ Tg) {
  __shared__ float T[64][68];
  __shared__ float S1[64][68];
  __shared__ float S2[64][68];
  __shared__ float row_s[64];
  const int bn = blockIdx.x;
  const size_t base = (size_t)bn * 64 * HID;
  const int tid = threadIdx.x;
  const int tr = tid >> 4, tc = tid & 15;
  float acc[4][4] = {{0.f}};
  for (int d0 = 0; d0 < HID; d0 += 64) {
    const int h = d0 >> 8;
#pragma unroll
    for (int p = 0; p < 4; ++p) {
      int rr = (tid >> 4) + (p << 4);
      int c4 = (tid & 15) << 2;
      float4 a = *(const float4*)&k[base + (size_t)rr * HID + d0 + c4];
      float bta = beta[(((bn << 6) + rr) << 2) + h];
      S2[c4 + 0][rr] = a.x; S2[c4 + 1][rr] = a.y;
      S2[c4 + 2][rr] = a.z; S2[c4 + 3][rr] = a.w;
      S1[c4 + 0][rr] = a.x * bta; S1[c4 + 1][rr] = a.y * bta;
      S1[c4 + 2][rr] = a.z * bta; S1[c4 + 3][rr] = a.w * bta;
    }
    __syncthreads();
#pragma unroll
    for (int dd = 0; dd < 64; ++dd) {
      float4 a = *(const float4*)&S1[dd][tr << 2];
      float4 b = *(const float4*)&S2[dd][tc << 2];
      acc[0][0] += a.x*b.x; acc[0][1] += a.x*b.y; acc[0][2] += a.x*b.z; acc[0][3] += a.x*b.w;
      acc[1][0] += a.y*b.x; acc[1][1] += a.y*b.y; acc[1][2] += a.y*b.z; acc[1][3] += a.y*b.w;
      acc[2][0] += a.z*b.x; acc[2][1] += a.z*b.y; acc[2][2] += a.z*b.z; acc[2][3] += a.z*b.w;
      acc[3][0] += a.w*b.x; acc[3][1] += a.w*b.y; acc[3][2] += a.w*b.z; acc[3][3] += a.w*b.w;
    }
    __syncthreads();
  }
#pragma unroll
  for (int i = 0; i < 4; ++i)
#pragma unroll
    for (int j = 0; j < 4; ++j) {
      int ri = (tr << 2) + i, cj = (tc << 2) + j;
      T[ri][cj] = (ri == cj) ? 1.f : (ri > cj ? -acc[i][j] : 0.f);
    }
  __syncthreads();
  for (int i = 1; i < 64; ++i) {
    if (tid < 64) row_s[tid] = T[i][tid];
    __syncthreads();
    if (tid < 64) {
      float a = 0.f;
#pragma unroll 8
      for (int j = 0; j < 64; ++j) a += row_s[j] * T[j][tid];
      if (tid < i) T[i][tid] = row_s[tid] + a;
    }
    __syncthreads();
  }
#pragma unroll
  for (int ii = 0; ii < 4; ++ii) {
    int off = (tid << 4) + (ii << 2);
    int c = off >> 6, j = off & 63;
    *(float4*)&Tg[(size_t)bn * 4096 + off] = *(const float4*)&T[c][j];
  }
}

// ---- P,R via ct[j,ch] = sum_c T[c,j]*k[c,ch] ----
template <typename ST>
__global__ __launch_bounds__(256)
void prct_kernel(const float* __restrict__ k, const ST* __restrict__ v,
                 const float* __restrict__ beta, const float* __restrict__ Tg,
                 float* __restrict__ P, float* __restrict__ R) {
  __shared__ float Ts[4096];
  __shared__ float bs[64];
  const int bn = blockIdx.x >> 2, h = blockIdx.x & 3;
  const int tid = threadIdx.x;
#pragma unroll
  for (int ii = 0; ii < 4; ++ii) {
    int off = (tid << 4) + (ii << 2);
    *(float4*)&Ts[off] = *(const float4*)&Tg[(size_t)bn * 4096 + off];
  }
  if (tid < 64) bs[tid] = beta[(((bn << 6) + tid) << 2) + h];
  __syncthreads();
  const int ch = (h << 8) + tid;
  const size_t base = (size_t)bn * 64 * HID;
  float ct[64];
#pragma unroll
  for (int j = 0; j < 64; ++j) ct[j] = 0.f;
  for (int c = 0; c < 64; ++c) {
    float kc = k[base + (size_t)c * HID + ch];
#pragma unroll
    for (int j = 0; j < 64; ++j) ct[j] += Ts[(c << 6) + j] * kc;
  }
  float p = 0.f, r = 0.f;
#pragma unroll
  for (int j = 0; j < 64; ++j) {
    float kj = k[base + (size_t)j * HID + ch];
    float vj = ldv(&v[base + (size_t)j * HID + ch]);
    p += bs[j] * kj * ct[j];
    r += vj * ct[j];
  }
  P[(size_t)bn * HID + ch] = p;
  R[(size_t)bn * HID + ch] = r;
}

// ---- diagonal scan ----
__global__ __launch_bounds__(256)
void scan_kernel(const float* __restrict__ P, const float* __restrict__ R,
                 float* __restrict__ Sdp) {
  const int b = blockIdx.x >> 2;
  const int ch = ((blockIdx.x & 3) << 8) + threadIdx.x;
  float S = 0.f;
  for (int n = 0; n < 64; ++n) {
    Sdp[(size_t)((n << 2) + b) * HID + ch] = S;
    float p = P[(size_t)((b << 6) + n) * HID + ch];
    float r = R[(size_t)((b << 6) + n) * HID + ch];
    S = S * (1.f - p) + r;
  }
}

// ---- osm rows c=0..3 ----
template <typename ST>
__global__ __launch_bounds__(256)
void osm_kernel(const float* __restrict__ k, const ST* __restrict__ v,
                const float* __restrict__ beta, const float* __restrict__ Tg,
                const float* __restrict__ Sdp, float* __restrict__ osm) {
  __shared__ float Ts4[4][64];
  __shared__ float bs[64];
  const int bn = blockIdx.x >> 2, h = blockIdx.x & 3;
  const int b = bn >> 6, n = bn & 63;
  const int tid = threadIdx.x;
  Ts4[tid >> 6][tid & 63] = Tg[(size_t)bn * 4096 + tid];
  if (tid < 64) bs[tid] = beta[(((bn << 6) + tid) << 2) + h];
  __syncthreads();
  const int ch = (h << 8) + tid;
  const size_t base = (size_t)bn * 64 * HID;
  float sd = Sdp[(size_t)((n << 2) + b) * HID + ch];
  float a0 = 0.f, a1 = 0.f, a2 = 0.f, a3 = 0.f;
  for (int j = 0; j < 64; ++j) {
    float kj = k[base + (size_t)j * HID + ch];
    float vj = ldv(&v[base + (size_t)j * HID + ch]);
    float w = vj - bs[j] * kj * sd;
    a0 += Ts4[0][j] * w; a1 += Ts4[1][j] * w;
    a2 += Ts4[2][j] * w; a3 += Ts4[3][j] * w;
  }
  osm[((size_t)(bn << 2) + 0) * HID + ch] = a0;
  osm[((size_t)(bn << 2) + 1) * HID + ch] = a1;
  osm[((size_t)(bn << 2) + 2) * HID + ch] = a2;
  osm[((size_t)(bn << 2) + 3) * HID + ch] = a3;
}

// ---- Ai ----
template <typename ST>
__global__ __launch_bounds__(256)
void ai_kernel(const ST* __restrict__ q, const float* __restrict__ k,
               float* __restrict__ Ai) {
  const int bn = blockIdx.x;
  const int b = bn >> 6;
  const int wave = threadIdx.x >> 6, lane = threadIdx.x & 63;
  const size_t roff = ((size_t)bn * 64 + wave) * HID;
  float s = 0.f;
#pragma unroll
  for (int it = 0; it < 4; ++it) {
    int d = (lane << 2) + (it << 8);
    float4 a = ld4(&q[roff + d]);
    float4 b4 = *(const float4*)&k[roff + d];
    s += a.x*b4.x + a.y*b4.y + a.z*b4.z + a.w*b4.w;
  }
#pragma unroll
  for (int off = 32; off; off >>= 1) s += __shfl_xor(s, off);
  if (lane == 0) Ai[(bn << 2) + wave] = (wave <= b) ? s : 0.f;
}

// ---- o = q*Sd + (c<=b)*Ai*osm, RMSNorm*g ; in-place over q ----
template <typename ST>
__global__ __launch_bounds__(256)
void o_kernel(ST* __restrict__ q, const float* __restrict__ Sdp,
              const float* __restrict__ osm, const float* __restrict__ Ai,
              const float* __restrict__ g) {
  const int row = blockIdx.x;
  const int b = row >> 12;
  const int l = row & (LL - 1);
  const int n = l >> 6, c = l & 63;
  const int ch = threadIdx.x << 2;
  const size_t ro = (size_t)row * HID;
  float4 qv = ld4(&q[ro + ch]);
  float4 sd = *(const float4*)&Sdp[(size_t)((n << 2) + b) * HID + ch];
  float ox = qv.x*sd.x, oy = qv.y*sd.y, oz = qv.z*sd.z, ow = qv.w*sd.w;
  if (c <= b) {
    int bn = (b << 6) + n;
    float a = Ai[(bn << 2) + c];
    float4 u = *(const float4*)&osm[((size_t)(bn << 2) + c) * HID + ch];
    ox += a * u.x; oy += a * u.y; oz += a * u.z; ow += a * u.w;
  }
  float ss = ox*ox + oy*oy + oz*oz + ow*ow;
#pragma unroll
  for (int off = 32; off; off >>= 1) ss += __shfl_xor(ss, off);
  float scale = 1.f / sqrtf(ss * (1.f / HD) + 1e-5f);
  float4 gv = *(const float4*)&g[ch & (HD - 1)];
  st4(&q[ro + ch], make_float4(ox*scale*gv.x, oy*scale*gv.y, oz*scale*gv.z, ow*scale*gv.w));
}

// ---- final S partials ----
template <typename ST>
__global__ __launch_bounds__(256)
void sfinal_part(const float* __restrict__ k, const ST* __restrict__ v,
                 const float* __restrict__ beta, const float* __restrict__ Tg,
                 const float* __restrict__ Sdp, float* __restrict__ Spart,
                 int ngroups, int npg) {
  __shared__ float Ts[4096];
  __shared__ float va[64][68];
  __shared__ float us[64][68];
  __shared__ float bs[64];
  const int ng = blockIdx.x % ngroups;
  const int be = blockIdx.x / ngroups;
  const int bh = be >> 2, eq = be & 3;
  const int b = bh >> 2, h = bh & 3;
  const int e0 = eq << 6;
  const int tid = threadIdx.x;
  float4 acc[16];
#pragma unroll
  for (int j4 = 0; j4 < 16; ++j4) acc[j4] = make_float4(0.f, 0.f, 0.f, 0.f);
  for (int n = ng * npg; n < ng * npg + npg; ++n) {
    const int bn = (b << 6) + n;
    const size_t base = (size_t)bn * 64 * HID;
    __syncthreads();
#pragma unroll
    for (int ii = 0; ii < 4; ++ii) {
      int off = (tid << 4) + (ii << 2);
      *(float4*)&Ts[off] = *(const float4*)&Tg[(size_t)bn * 4096 + off];
    }
    if (tid < 64) bs[tid] = beta[(((bn << 6) + tid) << 2) + h];
    __syncthreads();
#pragma unroll
    for (int p = 0; p < 16; ++p) {
      int idx = tid + (p << 8);
      int rr = idx >> 6, e = idx & 63;
      int chg = (h << 8) + e0 + e;
      float sdv = Sdp[(size_t)((n << 2) + b) * HID + chg];
      float kj = k[base + (size_t)rr * HID + chg];
      float vj = ldv(&v[base + (size_t)rr * HID + chg]);
      va[rr][e] = vj - bs[rr] * kj * sdv;
    }
    __syncthreads();
#pragma unroll
    for (int p = 0; p < 16; ++p) {
      int idx = tid + (p << 8);
      int c = idx >> 6, e = idx & 63;
      float s = 0.f;
#pragma unroll 16
      for (int j = 0; j < 64; ++j) s += Ts[(c << 6) + j] * va[j][e];
      us[c][e] = s;
    }
    __syncthreads();
    const int chd = (h << 8) + tid;
    for (int c = 0; c < 64; ++c) {
      float kv = k[base + (size_t)c * HID + chd];
#pragma unroll
      for (int j4 = 0; j4 < 16; ++j4) {
        float4 u4 = *(const float4*)&us[c][j4 << 2];
        acc[j4].x += kv*u4.x; acc[j4].y += kv*u4.y;
        acc[j4].z += kv*u4.z; acc[j4].w += kv*u4.w;
      }
    }
  }
  const size_t ob = (size_t)ng * SSIZE + ((size_t)(bh << 8) + tid) * HD + e0;
#pragma unroll
  for (int j4 = 0; j4 < 16; ++j4)
    *(float4*)&Spart[ob + (j4 << 2)] = acc[j4];
}

// ---- reduce partials -> Sout ----
__global__ __launch_bounds__(256)
void sreduce_kernel(const float* __restrict__ Spart, float* __restrict__ Sout,
                    int ngroups) {
  size_t i = ((size_t)blockIdx.x * 256 + threadIdx.x) << 2;
  float4 s = make_float4(0.f, 0.f, 0.f, 0.f);
  for (int g = 0; g < ngroups; ++g) {
    float4 p = *(const float4*)&Spart[(size_t)g * SSIZE + i];
    s.x += p.x; s.y += p.y; s.z += p.z; s.w += p.w;
  }
  *(float4*)&Sout[i] = s;
}

extern "C" void kernel_launch(void* const* d_in, const int* in_sizes, int n_in,
                              void* d_out, int out_size, void* d_ws, size_t ws_size,
                              hipStream_t stream) {
  const float* x  = (const float*)d_in[0];
  const float* Wq = (const float*)d_in[1];
  const float* Wk = (const float*)d_in[2];
  const float* Wv = (const float*)d_in[3];
  const float* Wb = (const float*)d_in[4];
  const float* cq = (const float*)d_in[5];
  const float* ck = (const float*)d_in[6];
  const float* cv = (const float*)d_in[7];
  const float* g  = (const float*)d_in[8];
  const float* Wo = (const float*)d_in[9];
  float* out  = (float*)d_out;
  float* Sout = out + (size_t)ROWS * HID;

  const size_t F = (size_t)ROWS * HID;
  char* w = (char*)d_ws;
  float* kbuf  = (float*)w;  w += F * 4;
  bf16*  xb    = (bf16*)w;   w += F * 2;   // Spart base later (with qbuf)
  bf16*  qbuf  = (bf16*)w;   w += F * 2;   // also xlo before conv<0>
  bf16*  vbuf  = (bf16*)w;   w += F * 2;
  unsigned short* Wqt  = (unsigned short*)w; w += (size_t)HID * HID * 2;
  unsigned short* Wvt  = (unsigned short*)w; w += (size_t)HID * HID * 2;
  unsigned short* Wot  = (unsigned short*)w; w += (size_t)HID * HID * 2;
  unsigned short* Wkht = (unsigned short*)w; w += (size_t)HID * HID * 2;
  unsigned short* Wklt = (unsigned short*)w; w += (size_t)HID * HID * 2;
  float* Tg    = (float*)w;  w += (size_t)BB * NCH * 4096 * 4;
  float* betab = (float*)w;  w += (size_t)ROWS * NH * 4;
  float* Aib   = (float*)w;  w += (size_t)BB * NCH * 4 * 4;
  float* Pb    = (float*)w;  w += (size_t)BB * NCH * HID * 4;
  float* Rb    = (float*)w;  w += (size_t)BB * NCH * HID * 4;
  float* Sdp   = (float*)w;  w += (size_t)BB * NCH * HID * 4;
  float* osmb  = (float*)w;  w += (size_t)BB * NCH * 4 * HID * 4;
  const size_t need = (size_t)(w - (char*)d_ws);
  if (ws_size < need) return;

  dim3 gg(ROWS / 128, HID / 128);
  dim3 gt(16, 16);
  float* lin = out;       // d_out[0..16M) scratch until final GEMM
  bf16* xlo = qbuf;       // alias: dead once conv<0> writes qbuf

  convX2_kernel<<<F / 1024, 256, 0, stream>>>(x, xb, xlo);
  convT2_kernel<<<gt, 256, 0, stream>>>(Wk, Wkht, Wklt);
  convT_kernel<<<gt, 256, 0, stream>>>(Wq, Wqt);
  convT_kernel<<<gt, 256, 0, stream>>>(Wv, Wvt);
  convT_kernel<<<gt, 256, 0, stream>>>(Wo, Wot);
  beta_kernel<<<ROWS / 4, 256, 0, stream>>>(x, Wb, betab);

  // k first (uses xlo which aliases qbuf)
  mfma_gemm3<<<gg, 256, 0, stream>>>((const unsigned short*)xb,
                                     (const unsigned short*)xlo, Wkht, Wklt, lin);
  conv_kernel<1, float><<<ROWS, 256, 0, stream>>>(lin, ck, betab, kbuf);
  mfma_gemm<<<gg, 256, 0, stream>>>((const unsigned short*)xb, Wqt, lin);
  conv_kernel<0, bf16><<<ROWS, 256, 0, stream>>>(lin, cq, betab, qbuf);
  mfma_gemm<<<gg, 256, 0, stream>>>((const unsigned short*)xb, Wvt, lin);
  conv_kernel<2, bf16><<<ROWS, 256, 0, stream>>>(lin, cv, betab, vbuf);

  chunkT_kernel<<<BB * NCH, 256, 0, stream>>>(kbuf, betab, Tg);
  prct_kernel<bf16><<<BB * NCH * NH, 256, 0, stream>>>(kbuf, vbuf, betab, Tg, Pb, Rb);
  scan_kernel<<<16, 256, 0, stream>>>(Pb, Rb, Sdp);
  osm_kernel<bf16><<<BB * NCH * NH, 256, 0, stream>>>(kbuf, vbuf, betab, Tg, Sdp, osmb);
  ai_kernel<bf16><<<BB * NCH, 256, 0, stream>>>(qbuf, kbuf, Aib);
  o_kernel<bf16><<<ROWS, 256, 0, stream>>>(qbuf, Sdp, osmb, Aib, g);
  mfma_gemm<<<gg, 256, 0, stream>>>((const unsigned short*)qbuf, Wot, out);

  // xb+qbuf (64MB) now dead -> 16-group fp32 partials for S
  float* Spart = (float*)xb;
  const int ngroups = 16, npg = 64 / ngroups;
  sfinal_part<bf16><<<64 * ngroups, 256, 0, stream>>>(kbuf, vbuf, betab, Tg,
                                                      Sdp, Spart, ngroups, npg);
  sreduce_kernel<<<SSIZE / 1024, 256, 0, stream>>>(Spart, Sout, ngroups);
}

// Round 12
// 838.905 us; speedup vs baseline: 10.0471x; 1.2807x over previous
//
#include <hip/hip_runtime.h>
#include <hip/hip_bf16.h>

#define HID 1024
#define NH 4
#define HD 256
#define NCH 64
#define BB 4
#define LL 4096
#define ROWS (BB*LL)
#define SSIZE (BB*NH*HD*HD)

typedef __hip_bfloat16 bf16;
typedef __attribute__((ext_vector_type(8))) short short8;
typedef __attribute__((ext_vector_type(4))) float f32x4;

struct u16x4 { unsigned short x, y, z, w; };

__device__ __forceinline__ float bfu2f(unsigned short u) {
  return __uint_as_float(((unsigned int)u) << 16);
}
__device__ __forceinline__ unsigned short f2bfu(float f) {
  unsigned int x = __float_as_uint(f);
  return (unsigned short)((x + 0x7FFFu + ((x >> 16) & 1u)) >> 16);
}
__device__ __forceinline__ float ldv(const float* p) { return *p; }
__device__ __forceinline__ float ldv(const bf16* p) { return bfu2f(*(const unsigned short*)p); }
__device__ __forceinline__ float4 ld4(const float* p) { return *(const float4*)p; }
__device__ __forceinline__ float4 ld4(const bf16* p) {
  u16x4 u = *(const u16x4*)p;
  return make_float4(bfu2f(u.x), bfu2f(u.y), bfu2f(u.z), bfu2f(u.w));
}
__device__ __forceinline__ void st4(float* p, float4 v) { *(float4*)p = v; }
__device__ __forceinline__ void st4(bf16* p, float4 v) {
  u16x4 u; u.x = f2bfu(v.x); u.y = f2bfu(v.y); u.z = f2bfu(v.z); u.w = f2bfu(v.w);
  *(u16x4*)p = u;
}

typedef const __attribute__((address_space(1))) unsigned int* gptr_t;
typedef __attribute__((address_space(3))) unsigned int* lptr_t;
__device__ __forceinline__ void gload16(const void* g, void* l) {
  __builtin_amdgcn_global_load_lds((gptr_t)g, (lptr_t)l, 16, 0, 0);
}

// ---------------- beta = sigmoid(x @ Wb) ----------------
__global__ __launch_bounds__(256)
void beta_kernel(const float* __restrict__ x, const float* __restrict__ Wb,
                 float* __restrict__ beta) {
  const int wave = threadIdx.x >> 6, lane = threadIdx.x & 63;
  const int m = (blockIdx.x << 2) + wave;
  const float* xr = x + (size_t)m * HID;
  float a0 = 0.f, a1 = 0.f, a2 = 0.f, a3 = 0.f;
#pragma unroll
  for (int it = 0; it < 16; ++it) {
    int kk = lane + (it << 6);
    float xv = xr[kk];
    float4 w = *(const float4*)&Wb[kk << 2];
    a0 += xv * w.x; a1 += xv * w.y; a2 += xv * w.z; a3 += xv * w.w;
  }
#pragma unroll
  for (int off = 32; off; off >>= 1) {
    a0 += __shfl_xor(a0, off); a1 += __shfl_xor(a1, off);
    a2 += __shfl_xor(a2, off); a3 += __shfl_xor(a3, off);
  }
  if (lane == 0) {
    float4 r;
    r.x = 1.f / (1.f + expf(-a0)); r.y = 1.f / (1.f + expf(-a1));
    r.z = 1.f / (1.f + expf(-a2)); r.w = 1.f / (1.f + expf(-a3));
    *(float4*)&beta[m << 2] = r;
  }
}

// ---- convert x -> hi (bf16) + lo (bf16 of residual) ----
__global__ __launch_bounds__(256)
void convX2_kernel(const float* __restrict__ x, bf16* __restrict__ hi,
                   bf16* __restrict__ lo) {
  size_t i = ((size_t)blockIdx.x * 256 + threadIdx.x) << 2;
  float4 v = *(const float4*)&x[i];
  u16x4 h; h.x = f2bfu(v.x); h.y = f2bfu(v.y); h.z = f2bfu(v.z); h.w = f2bfu(v.w);
  *(u16x4*)&hi[i] = h;
  u16x4 l;
  l.x = f2bfu(v.x - bfu2f(h.x)); l.y = f2bfu(v.y - bfu2f(h.y));
  l.z = f2bfu(v.z - bfu2f(h.z)); l.w = f2bfu(v.w - bfu2f(h.w));
  *(u16x4*)&lo[i] = l;
}

// ---- convert + transpose weight: Wt[n][k] = bf16(W[k][n]) ----
__global__ __launch_bounds__(256)
void convT_kernel(const float* __restrict__ W, unsigned short* __restrict__ Wt) {
  __shared__ unsigned short t[64][68];
  const int kt = blockIdx.x << 6, nt = blockIdx.y << 6;
  const int tid = threadIdx.x;
#pragma unroll
  for (int i = 0; i < 16; ++i) {
    int idx = tid + (i << 8);
    int r = idx >> 6, c = idx & 63;
    t[r][c] = f2bfu(W[(size_t)(kt + r) * HID + nt + c]);
  }
  __syncthreads();
#pragma unroll
  for (int i = 0; i < 16; ++i) {
    int idx = tid + (i << 8);
    int n = idx >> 6, kk = idx & 63;
    Wt[(size_t)(nt + n) * HID + kt + kk] = t[kk][n];
  }
}

// ---- convert + transpose weight into hi/lo bf16 pair ----
__global__ __launch_bounds__(256)
void convT2_kernel(const float* __restrict__ W, unsigned short* __restrict__ Wht,
                   unsigned short* __restrict__ Wlt) {
  __shared__ float t[64][65];
  const int kt = blockIdx.x << 6, nt = blockIdx.y << 6;
  const int tid = threadIdx.x;
#pragma unroll
  for (int i = 0; i < 16; ++i) {
    int idx = tid + (i << 8);
    int r = idx >> 6, c = idx & 63;
    t[r][c] = W[(size_t)(kt + r) * HID + nt + c];
  }
  __syncthreads();
#pragma unroll
  for (int i = 0; i < 16; ++i) {
    int idx = tid + (i << 8);
    int n = idx >> 6, kk = idx & 63;
    float v = t[kk][n];
    unsigned short h = f2bfu(v);
    Wht[(size_t)(nt + n) * HID + kt + kk] = h;
    Wlt[(size_t)(nt + n) * HID + kt + kk] = f2bfu(v - bfu2f(h));
  }
}

// ---- transpose k: kt[ch][row] = bf16(kbuf[row][ch]) ----
__global__ __launch_bounds__(256)
void ktrans_kernel(const float* __restrict__ k, unsigned short* __restrict__ kt) {
  __shared__ float t[64][65];
  const int r0 = blockIdx.x << 6, c0 = blockIdx.y << 6;
  const int tid = threadIdx.x;
#pragma unroll
  for (int i = 0; i < 16; ++i) {
    int idx = tid + (i << 8);
    int rr = idx >> 6, cc = idx & 63;
    t[rr][cc] = k[(size_t)(r0 + rr) * HID + c0 + cc];
  }
  __syncthreads();
#pragma unroll
  for (int i = 0; i < 16; ++i) {
    int idx = tid + (i << 8);
    int cc = idx >> 6, rr = idx & 63;
    kt[(size_t)(c0 + cc) * ROWS + r0 + rr] = f2bfu(t[rr][cc]);
  }
}

// ---- bf16 MFMA GEMM: C = A @ Bt^T (Bt pre-transposed bf16) ----
__global__ __launch_bounds__(256)
void mfma_gemm(const unsigned short* __restrict__ A,
               const unsigned short* __restrict__ Bt, float* __restrict__ C) {
  __shared__ unsigned short Asl[128 * 32];
  __shared__ unsigned short Bsl[128 * 32];
  const int tid = threadIdx.x;
  const int wave = tid >> 6, lane = tid & 63;
  const int m0 = blockIdx.x << 7, n0 = blockIdx.y << 7;
  const int wr = wave >> 1, wc = wave & 1;
  f32x4 acc[4][4] = {};
  const int cA = (wave << 6) + lane;
  for (int k0 = 0; k0 < HID; k0 += 32) {
#pragma unroll
    for (int i = 0; i < 2; ++i) {
      int c = cA + (i << 8);
      int row = c >> 2, ko = (c & 3) << 3;
      gload16(&A[(size_t)(m0 + row) * HID + k0 + ko],
              &Asl[(size_t)((i << 8) + (wave << 6)) * 8]);
      gload16(&Bt[(size_t)(n0 + row) * HID + k0 + ko],
              &Bsl[(size_t)((i << 8) + (wave << 6)) * 8]);
    }
    __syncthreads();
    short8 af[4], bfr[4];
#pragma unroll
    for (int f = 0; f < 4; ++f) {
      int ra = (wr << 6) + (f << 4) + (lane & 15);
      af[f] = *(const short8*)&Asl[ra * 32 + ((lane >> 4) << 3)];
      int rb = (wc << 6) + (f << 4) + (lane & 15);
      bfr[f] = *(const short8*)&Bsl[rb * 32 + ((lane >> 4) << 3)];
    }
#pragma unroll
    for (int i = 0; i < 4; ++i)
#pragma unroll
      for (int j = 0; j < 4; ++j)
        acc[i][j] = __builtin_amdgcn_mfma_f32_16x16x32_bf16(af[i], bfr[j],
                                                            acc[i][j], 0, 0, 0);
    __syncthreads();
  }
#pragma unroll
  for (int i = 0; i < 4; ++i) {
    int r0 = m0 + (wr << 6) + (i << 4) + ((lane >> 4) << 2);
#pragma unroll
    for (int j = 0; j < 4; ++j) {
      int c0 = n0 + (wc << 6) + (j << 4) + (lane & 15);
#pragma unroll
      for (int r = 0; r < 4; ++r)
        C[(size_t)(r0 + r) * HID + c0] = acc[i][j][r];
    }
  }
}

// ---- split-bf16 MFMA GEMM: C = (Ah+Al) @ (Bh+Bl)^T, dropping Al*Bl ----
__global__ __launch_bounds__(256)
void mfma_gemm3(const unsigned short* __restrict__ Ah_,
                const unsigned short* __restrict__ Al_,
                const unsigned short* __restrict__ Bh_,
                const unsigned short* __restrict__ Bl_,
                float* __restrict__ C) {
  __shared__ unsigned short Ah[128 * 32];
  __shared__ unsigned short Al[128 * 32];
  __shared__ unsigned short Bh[128 * 32];
  __shared__ unsigned short Bl[128 * 32];
  const int tid = threadIdx.x;
  const int wave = tid >> 6, lane = tid & 63;
  const int m0 = blockIdx.x << 7, n0 = blockIdx.y << 7;
  const int wr = wave >> 1, wc = wave & 1;
  f32x4 acc[4][4] = {};
  const int cA = (wave << 6) + lane;
  for (int k0 = 0; k0 < HID; k0 += 32) {
#pragma unroll
    for (int i = 0; i < 2; ++i) {
      int c = cA + (i << 8);
      int row = c >> 2, ko = (c & 3) << 3;
      size_t ga = (size_t)(m0 + row) * HID + k0 + ko;
      size_t gb = (size_t)(n0 + row) * HID + k0 + ko;
      size_t ldst = (size_t)((i << 8) + (wave << 6)) * 8;
      gload16(&Ah_[ga], &Ah[ldst]);
      gload16(&Al_[ga], &Al[ldst]);
      gload16(&Bh_[gb], &Bh[ldst]);
      gload16(&Bl_[gb], &Bl[ldst]);
    }
    __syncthreads();
    short8 ah[4], al[4], bh[4], bl[4];
#pragma unroll
    for (int f = 0; f < 4; ++f) {
      int ra = ((wr << 6) + (f << 4) + (lane & 15)) * 32 + ((lane >> 4) << 3);
      ah[f] = *(const short8*)&Ah[ra];
      al[f] = *(const short8*)&Al[ra];
      int rb = ((wc << 6) + (f << 4) + (lane & 15)) * 32 + ((lane >> 4) << 3);
      bh[f] = *(const short8*)&Bh[rb];
      bl[f] = *(const short8*)&Bl[rb];
    }
#pragma unroll
    for (int i = 0; i < 4; ++i)
#pragma unroll
      for (int j = 0; j < 4; ++j) {
        f32x4 a = acc[i][j];
        a = __builtin_amdgcn_mfma_f32_16x16x32_bf16(al[i], bh[j], a, 0, 0, 0);
        a = __builtin_amdgcn_mfma_f32_16x16x32_bf16(ah[i], bl[j], a, 0, 0, 0);
        a = __builtin_amdgcn_mfma_f32_16x16x32_bf16(ah[i], bh[j], a, 0, 0, 0);
        acc[i][j] = a;
      }
    __syncthreads();
  }
#pragma unroll
  for (int i = 0; i < 4; ++i) {
    int r0 = m0 + (wr << 6) + (i << 4) + ((lane >> 4) << 2);
#pragma unroll
    for (int j = 0; j < 4; ++j) {
      int c0 = n0 + (wc << 6) + (j << 4) + (lane & 15);
#pragma unroll
      for (int r = 0; r < 4; ++r)
        C[(size_t)(r0 + r) * HID + c0] = acc[i][j][r];
    }
  }
}

// ---- MFMA GEMM for S: C[256x256] += A[m][K]·B[n][K] per (bh, K-group) ----
// A = kt rows (h*256+d), B = Ut rows (bh*256+e); K-slice = b*4096 + ng*512.
__global__ __launch_bounds__(256)
void mfma_gemmS(const unsigned short* __restrict__ At,
                const unsigned short* __restrict__ Bt,
                float* __restrict__ Spart, int ngroups) {
  __shared__ unsigned short Asl[128 * 32];
  __shared__ unsigned short Bsl[128 * 32];
  const int tid = threadIdx.x;
  const int wave = tid >> 6, lane = tid & 63;
  const int m0 = blockIdx.x << 7, n0 = blockIdx.y << 7;
  const int bh = blockIdx.z / ngroups;
  const int ng = blockIdx.z % ngroups;
  const int b = bh >> 2, h = bh & 3;
  const int klen = (LL >> 3) * 8 / ngroups * 8;  // 4096/ngroups
  const size_t kbase = (size_t)b * LL + (size_t)ng * (LL / ngroups);
  const unsigned short* A = At + (size_t)(h * HD) * ROWS + kbase;
  const unsigned short* B = Bt + (size_t)(bh * HD) * ROWS / BB + kbase;
  // note: Ut row stride is 4096 (= LL), base offset bh*256 rows
  const int wr = wave >> 1, wc = wave & 1;
  f32x4 acc[4][4] = {};
  const int cA = (wave << 6) + lane;
  for (int k0 = 0; k0 < LL / ngroups; k0 += 32) {
#pragma unroll
    for (int i = 0; i < 2; ++i) {
      int c = cA + (i << 8);
      int row = c >> 2, ko = (c & 3) << 3;
      gload16(&At[((size_t)(h * HD + m0 + row)) * ROWS + kbase + k0 + ko],
              &Asl[(size_t)((i << 8) + (wave << 6)) * 8]);
      gload16(&Bt[((size_t)(bh * HD + n0 + row)) * LL + (size_t)ng * (LL / ngroups) + k0 + ko],
              &Bsl[(size_t)((i << 8) + (wave << 6)) * 8]);
    }
    __syncthreads();
    short8 af[4], bfr[4];
#pragma unroll
    for (int f = 0; f < 4; ++f) {
      int ra = (wr << 6) + (f << 4) + (lane & 15);
      af[f] = *(const short8*)&Asl[ra * 32 + ((lane >> 4) << 3)];
      int rb = (wc << 6) + (f << 4) + (lane & 15);
      bfr[f] = *(const short8*)&Bsl[rb * 32 + ((lane >> 4) << 3)];
    }
#pragma unroll
    for (int i = 0; i < 4; ++i)
#pragma unroll
      for (int j = 0; j < 4; ++j)
        acc[i][j] = __builtin_amdgcn_mfma_f32_16x16x32_bf16(af[i], bfr[j],
                                                            acc[i][j], 0, 0, 0);
    __syncthreads();
  }
  float* Cp = Spart + (size_t)ng * SSIZE + (size_t)bh * HD * HD;
#pragma unroll
  for (int i = 0; i < 4; ++i) {
    int r0 = m0 + (wr << 6) + (i << 4) + ((lane >> 4) << 2);
#pragma unroll
    for (int j = 0; j < 4; ++j) {
      int c0 = n0 + (wc << 6) + (j << 4) + (lane & 15);
#pragma unroll
      for (int r = 0; r < 4; ++r)
        Cp[(size_t)(r0 + r) * HD + c0] = acc[i][j][r];
    }
  }
}

// ------- causal depthwise conv(K=4) + SiLU (+L2 norm / +beta) -------
template <int MODE, typename ST>
__global__ __launch_bounds__(256)
void conv_kernel(const float* __restrict__ lin, const float* __restrict__ w,
                 const float* __restrict__ beta, ST* __restrict__ out) {
  const int row = blockIdx.x;
  const int l = row & (LL - 1);
  const int tid = threadIdx.x;
  const int ch = tid << 2;
  float wv[4][4];
#pragma unroll
  for (int j = 0; j < 4; ++j) {
    float4 t4 = *(const float4*)&w[(ch + j) << 2];
    wv[j][0] = t4.x; wv[j][1] = t4.y; wv[j][2] = t4.z; wv[j][3] = t4.w;
  }
  float y[4] = {0.f, 0.f, 0.f, 0.f};
#pragma unroll
  for (int t = 0; t < 4; ++t) {
    if (l - 3 + t >= 0) {
      float4 xv = *(const float4*)&lin[(size_t)(row - 3 + t) * HID + ch];
      y[0] += xv.x * wv[0][t]; y[1] += xv.y * wv[1][t];
      y[2] += xv.z * wv[2][t]; y[3] += xv.w * wv[3][t];
    }
  }
#pragma unroll
  for (int j = 0; j < 4; ++j) y[j] = y[j] / (1.f + expf(-y[j]));
  float scale;
  if (MODE < 2) {
    float ss = y[0]*y[0] + y[1]*y[1] + y[2]*y[2] + y[3]*y[3];
#pragma unroll
    for (int off = 32; off; off >>= 1) ss += __shfl_xor(ss, off);
    scale = 1.f / sqrtf(ss);
  } else {
    scale = beta[(row << 2) + (tid >> 6)];
  }
  st4(&out[(size_t)row * HID + ch],
      make_float4(y[0]*scale, y[1]*scale, y[2]*scale, y[3]*scale));
}

// ---- per-(b,n): T recurrence (fp32), store T ----
__global__ __launch_bounds__(256)
void chunkT_kernel(const float* __restrict__ k, const float* __restrict__ beta,
                   float* __restrict__ Tg) {
  __shared__ float T[64][68];
  __shared__ float S1[64][68];
  __shared__ float S2[64][68];
  __shared__ float row_s[64];
  const int bn = blockIdx.x;
  const size_t base = (size_t)bn * 64 * HID;
  const int tid = threadIdx.x;
  const int tr = tid >> 4, tc = tid & 15;
  float acc[4][4] = {{0.f}};
  for (int d0 = 0; d0 < HID; d0 += 64) {
    const int h = d0 >> 8;
#pragma unroll
    for (int p = 0; p < 4; ++p) {
      int rr = (tid >> 4) + (p << 4);
      int c4 = (tid & 15) << 2;
      float4 a = *(const float4*)&k[base + (size_t)rr * HID + d0 + c4];
      float bta = beta[(((bn << 6) + rr) << 2) + h];
      S2[c4 + 0][rr] = a.x; S2[c4 + 1][rr] = a.y;
      S2[c4 + 2][rr] = a.z; S2[c4 + 3][rr] = a.w;
      S1[c4 + 0][rr] = a.x * bta; S1[c4 + 1][rr] = a.y * bta;
      S1[c4 + 2][rr] = a.z * bta; S1[c4 + 3][rr] = a.w * bta;
    }
    __syncthreads();
#pragma unroll
    for (int dd = 0; dd < 64; ++dd) {
      float4 a = *(const float4*)&S1[dd][tr << 2];
      float4 b = *(const float4*)&S2[dd][tc << 2];
      acc[0][0] += a.x*b.x; acc[0][1] += a.x*b.y; acc[0][2] += a.x*b.z; acc[0][3] += a.x*b.w;
      acc[1][0] += a.y*b.x; acc[1][1] += a.y*b.y; acc[1][2] += a.y*b.z; acc[1][3] += a.y*b.w;
      acc[2][0] += a.z*b.x; acc[2][1] += a.z*b.y; acc[2][2] += a.z*b.z; acc[2][3] += a.z*b.w;
      acc[3][0] += a.w*b.x; acc[3][1] += a.w*b.y; acc[3][2] += a.w*b.z; acc[3][3] += a.w*b.w;
    }
    __syncthreads();
  }
#pragma unroll
  for (int i = 0; i < 4; ++i)
#pragma unroll
    for (int j = 0; j < 4; ++j) {
      int ri = (tr << 2) + i, cj = (tc << 2) + j;
      T[ri][cj] = (ri == cj) ? 1.f : (ri > cj ? -acc[i][j] : 0.f);
    }
  __syncthreads();
  for (int i = 1; i < 64; ++i) {
    if (tid < 64) row_s[tid] = T[i][tid];
    __syncthreads();
    if (tid < 64) {
      float a = 0.f;
#pragma unroll 8
      for (int j = 0; j < 64; ++j) a += row_s[j] * T[j][tid];
      if (tid < i) T[i][tid] = row_s[tid] + a;
    }
    __syncthreads();
  }
#pragma unroll
  for (int ii = 0; ii < 4; ++ii) {
    int off = (tid << 4) + (ii << 2);
    int c = off >> 6, j = off & 63;
    *(float4*)&Tg[(size_t)bn * 4096 + off] = *(const float4*)&T[c][j];
  }
}

// ---- P,R via ct[j,ch] = sum_c T[c,j]*k[c,ch] ----
template <typename ST>
__global__ __launch_bounds__(256)
void prct_kernel(const float* __restrict__ k, const ST* __restrict__ v,
                 const float* __restrict__ beta, const float* __restrict__ Tg,
                 float* __restrict__ P, float* __restrict__ R) {
  __shared__ float Ts[4096];
  __shared__ float bs[64];
  const int bn = blockIdx.x >> 2, h = blockIdx.x & 3;
  const int tid = threadIdx.x;
#pragma unroll
  for (int ii = 0; ii < 4; ++ii) {
    int off = (tid << 4) + (ii << 2);
    *(float4*)&Ts[off] = *(const float4*)&Tg[(size_t)bn * 4096 + off];
  }
  if (tid < 64) bs[tid] = beta[(((bn << 6) + tid) << 2) + h];
  __syncthreads();
  const int ch = (h << 8) + tid;
  const size_t base = (size_t)bn * 64 * HID;
  float ct[64];
#pragma unroll
  for (int j = 0; j < 64; ++j) ct[j] = 0.f;
  for (int c = 0; c < 64; ++c) {
    float kc = k[base + (size_t)c * HID + ch];
#pragma unroll
    for (int j = 0; j < 64; ++j) ct[j] += Ts[(c << 6) + j] * kc;
  }
  float p = 0.f, r = 0.f;
#pragma unroll
  for (int j = 0; j < 64; ++j) {
    float kj = k[base + (size_t)j * HID + ch];
    float vj = ldv(&v[base + (size_t)j * HID + ch]);
    p += bs[j] * kj * ct[j];
    r += vj * ct[j];
  }
  P[(size_t)bn * HID + ch] = p;
  R[(size_t)bn * HID + ch] = r;
}

// ---- diagonal scan ----
__global__ __launch_bounds__(256)
void scan_kernel(const float* __restrict__ P, const float* __restrict__ R,
                 float* __restrict__ Sdp) {
  const int b = blockIdx.x >> 2;
  const int ch = ((blockIdx.x & 3) << 8) + threadIdx.x;
  float S = 0.f;
  for (int n = 0; n < 64; ++n) {
    Sdp[(size_t)((n << 2) + b) * HID + ch] = S;
    float p = P[(size_t)((b << 6) + n) * HID + ch];
    float r = R[(size_t)((b << 6) + n) * HID + ch];
    S = S * (1.f - p) + r;
  }
}

// ---- osm rows c=0..3 ----
template <typename ST>
__global__ __launch_bounds__(256)
void osm_kernel(const float* __restrict__ k, const ST* __restrict__ v,
                const float* __restrict__ beta, const float* __restrict__ Tg,
                const float* __restrict__ Sdp, float* __restrict__ osm) {
  __shared__ float Ts4[4][64];
  __shared__ float bs[64];
  const int bn = blockIdx.x >> 2, h = blockIdx.x & 3;
  const int b = bn >> 6, n = bn & 63;
  const int tid = threadIdx.x;
  Ts4[tid >> 6][tid & 63] = Tg[(size_t)bn * 4096 + tid];
  if (tid < 64) bs[tid] = beta[(((bn << 6) + tid) << 2) + h];
  __syncthreads();
  const int ch = (h << 8) + tid;
  const size_t base = (size_t)bn * 64 * HID;
  float sd = Sdp[(size_t)((n << 2) + b) * HID + ch];
  float a0 = 0.f, a1 = 0.f, a2 = 0.f, a3 = 0.f;
  for (int j = 0; j < 64; ++j) {
    float kj = k[base + (size_t)j * HID + ch];
    float vj = ldv(&v[base + (size_t)j * HID + ch]);
    float w = vj - bs[j] * kj * sd;
    a0 += Ts4[0][j] * w; a1 += Ts4[1][j] * w;
    a2 += Ts4[2][j] * w; a3 += Ts4[3][j] * w;
  }
  osm[((size_t)(bn << 2) + 0) * HID + ch] = a0;
  osm[((size_t)(bn << 2) + 1) * HID + ch] = a1;
  osm[((size_t)(bn << 2) + 2) * HID + ch] = a2;
  osm[((size_t)(bn << 2) + 3) * HID + ch] = a3;
}

// ---- Ai ----
template <typename ST>
__global__ __launch_bounds__(256)
void ai_kernel(const ST* __restrict__ q, const float* __restrict__ k,
               float* __restrict__ Ai) {
  const int bn = blockIdx.x;
  const int b = bn >> 6;
  const int wave = threadIdx.x >> 6, lane = threadIdx.x & 63;
  const size_t roff = ((size_t)bn * 64 + wave) * HID;
  float s = 0.f;
#pragma unroll
  for (int it = 0; it < 4; ++it) {
    int d = (lane << 2) + (it << 8);
    float4 a = ld4(&q[roff + d]);
    float4 b4 = *(const float4*)&k[roff + d];
    s += a.x*b4.x + a.y*b4.y + a.z*b4.z + a.w*b4.w;
  }
#pragma unroll
  for (int off = 32; off; off >>= 1) s += __shfl_xor(s, off);
  if (lane == 0) Ai[(bn << 2) + wave] = (wave <= b) ? s : 0.f;
}

// ---- o = q*Sd + (c<=b)*Ai*osm, RMSNorm*g ; in-place over q ----
template <typename ST>
__global__ __launch_bounds__(256)
void o_kernel(ST* __restrict__ q, const float* __restrict__ Sdp,
              const float* __restrict__ osm, const float* __restrict__ Ai,
              const float* __restrict__ g) {
  const int row = blockIdx.x;
  const int b = row >> 12;
  const int l = row & (LL - 1);
  const int n = l >> 6, c = l & 63;
  const int ch = threadIdx.x << 2;
  const size_t ro = (size_t)row * HID;
  float4 qv = ld4(&q[ro + ch]);
  float4 sd = *(const float4*)&Sdp[(size_t)((n << 2) + b) * HID + ch];
  float ox = qv.x*sd.x, oy = qv.y*sd.y, oz = qv.z*sd.z, ow = qv.w*sd.w;
  if (c <= b) {
    int bn = (b << 6) + n;
    float a = Ai[(bn << 2) + c];
    float4 u = *(const float4*)&osm[((size_t)(bn << 2) + c) * HID + ch];
    ox += a * u.x; oy += a * u.y; oz += a * u.z; ow += a * u.w;
  }
  float ss = ox*ox + oy*oy + oz*oz + ow*ow;
#pragma unroll
  for (int off = 32; off; off >>= 1) ss += __shfl_xor(ss, off);
  float scale = 1.f / sqrtf(ss * (1.f / HD) + 1e-5f);
  float4 gv = *(const float4*)&g[ch & (HD - 1)];
  st4(&q[ro + ch], make_float4(ox*scale*gv.x, oy*scale*gv.y, oz*scale*gv.z, ow*scale*gv.w));
}

// ---- ucompute: u = T@(v - beta*k*Sd) in fp32, write Ut[bh*256+e][row] bf16 ----
// block = (bn, h, e-half); thread owns e = tid&127, c-half = tid>>7 (32 c's).
__global__ __launch_bounds__(256)
void ucompute_kernel(const float* __restrict__ k, const bf16* __restrict__ v,
                     const float* __restrict__ beta, const float* __restrict__ Tg,
                     const float* __restrict__ Sdp, unsigned short* __restrict__ Ut) {
  __shared__ float Ts[4096];
  __shared__ float va[64][132];
  __shared__ float bs[64];
  const int bn = blockIdx.x >> 3;
  const int rr2 = blockIdx.x & 7;
  const int h = rr2 >> 1, eh = rr2 & 1;
  const int b = bn >> 6, nl = bn & 63;
  const int tid = threadIdx.x;
#pragma unroll
  for (int ii = 0; ii < 4; ++ii) {
    int off = (tid << 4) + (ii << 2);
    *(float4*)&Ts[off] = *(const float4*)&Tg[(size_t)bn * 4096 + off];
  }
  if (tid < 64) bs[tid] = beta[(((bn << 6) + tid) << 2) + h];
  __syncthreads();
  const size_t base = (size_t)bn * 64 * HID;
  const int ch0 = (h << 8) + (eh << 7);
#pragma unroll
  for (int p = 0; p < 8; ++p) {
    int idx = tid + (p << 8);            // 0..2047 float4 groups
    int row = idx >> 5;                  // 32 groups per row (128 e / 4)
    int col4 = (idx & 31) << 2;
    int chg = ch0 + col4;
    float4 sd4 = *(const float4*)&Sdp[(size_t)((nl << 2) + b) * HID + chg];
    float4 k4 = *(const float4*)&k[base + (size_t)row * HID + chg];
    float4 v4 = ld4(&v[base + (size_t)row * HID + chg]);
    float bt = bs[row];
    va[row][col4 + 0] = v4.x - bt * k4.x * sd4.x;
    va[row][col4 + 1] = v4.y - bt * k4.y * sd4.y;
    va[row][col4 + 2] = v4.z - bt * k4.z * sd4.z;
    va[row][col4 + 3] = v4.w - bt * k4.w * sd4.w;
  }
  __syncthreads();
  const int e = tid & 127;
  const int chalf = tid >> 7;
  float acc[32];
#pragma unroll
  for (int c2 = 0; c2 < 32; ++c2) acc[c2] = 0.f;
  for (int j = 0; j < 64; ++j) {
    float vaj = va[j][e];
#pragma unroll
    for (int c2 = 0; c2 < 32; ++c2)
      acc[c2] += Ts[((chalf << 5) + c2) * 64 + j] * vaj;
  }
  // Ut row = bh*256 + (eh*128 + e); col = nl*64 + chalf*32 + c2
  const size_t ub = ((size_t)(((b << 2) + h) * HD) + (eh << 7) + e) * LL
                  + (nl << 6) + (chalf << 5);
#pragma unroll
  for (int c4 = 0; c4 < 8; ++c4) {
    u16x4 u;
    u.x = f2bfu(acc[(c4 << 2) + 0]); u.y = f2bfu(acc[(c4 << 2) + 1]);
    u.z = f2bfu(acc[(c4 << 2) + 2]); u.w = f2bfu(acc[(c4 << 2) + 3]);
    *(u16x4*)&Ut[ub + (c4 << 2)] = u;
  }
}

// ---- reduce partials -> Sout ----
__global__ __launch_bounds__(256)
void sreduce_kernel(const float* __restrict__ Spart, float* __restrict__ Sout,
                    int ngroups) {
  size_t i = ((size_t)blockIdx.x * 256 + threadIdx.x) << 2;
  float4 s = make_float4(0.f, 0.f, 0.f, 0.f);
  for (int g = 0; g < ngroups; ++g) {
    float4 p = *(const float4*)&Spart[(size_t)g * SSIZE + i];
    s.x += p.x; s.y += p.y; s.z += p.z; s.w += p.w;
  }
  *(float4*)&Sout[i] = s;
}

extern "C" void kernel_launch(void* const* d_in, const int* in_sizes, int n_in,
                              void* d_out, int out_size, void* d_ws, size_t ws_size,
                              hipStream_t stream) {
  const float* x  = (const float*)d_in[0];
  const float* Wq = (const float*)d_in[1];
  const float* Wk = (const float*)d_in[2];
  const float* Wv = (const float*)d_in[3];
  const float* Wb = (const float*)d_in[4];
  const float* cq = (const float*)d_in[5];
  const float* ck = (const float*)d_in[6];
  const float* cv = (const float*)d_in[7];
  const float* g  = (const float*)d_in[8];
  const float* Wo = (const float*)d_in[9];
  float* out  = (float*)d_out;
  float* Sout = out + (size_t)ROWS * HID;

  const size_t F = (size_t)ROWS * HID;
  char* w = (char*)d_ws;
  float* kbuf  = (float*)w;  w += F * 4;   // -> Spart after ucompute
  bf16*  xb    = (bf16*)w;   w += F * 2;   // -> kt after v-GEMM
  bf16*  qbuf  = (bf16*)w;   w += F * 2;   // xlo first, then q, then Ut
  bf16*  vbuf  = (bf16*)w;   w += F * 2;
  unsigned short* Wqt  = (unsigned short*)w; w += (size_t)HID * HID * 2;
  unsigned short* Wvt  = (unsigned short*)w; w += (size_t)HID * HID * 2;
  unsigned short* Wot  = (unsigned short*)w; w += (size_t)HID * HID * 2;
  unsigned short* Wkht = (unsigned short*)w; w += (size_t)HID * HID * 2;
  unsigned short* Wklt = (unsigned short*)w; w += (size_t)HID * HID * 2;
  float* Tg    = (float*)w;  w += (size_t)BB * NCH * 4096 * 4;
  float* betab = (float*)w;  w += (size_t)ROWS * NH * 4;
  float* Aib   = (float*)w;  w += (size_t)BB * NCH * 4 * 4;
  float* Pb    = (float*)w;  w += (size_t)BB * NCH * HID * 4;
  float* Rb    = (float*)w;  w += (size_t)BB * NCH * HID * 4;
  float* Sdp   = (float*)w;  w += (size_t)BB * NCH * HID * 4;
  float* osmb  = (float*)w;  w += (size_t)BB * NCH * 4 * HID * 4;
  const size_t need = (size_t)(w - (char*)d_ws);
  if (ws_size < need) return;

  dim3 gg(ROWS / 128, HID / 128);
  dim3 gt(16, 16);
  float* lin = out;       // d_out[0..16M) scratch until final GEMM
  bf16* xlo = qbuf;       // alias: dead once conv<0> writes qbuf

  convX2_kernel<<<F / 1024, 256, 0, stream>>>(x, xb, xlo);
  convT2_kernel<<<gt, 256, 0, stream>>>(Wk, Wkht, Wklt);
  convT_kernel<<<gt, 256, 0, stream>>>(Wq, Wqt);
  convT_kernel<<<gt, 256, 0, stream>>>(Wv, Wvt);
  convT_kernel<<<gt, 256, 0, stream>>>(Wo, Wot);
  beta_kernel<<<ROWS / 4, 256, 0, stream>>>(x, Wb, betab);

  // k first (uses xlo which aliases qbuf)
  mfma_gemm3<<<gg, 256, 0, stream>>>((const unsigned short*)xb,
                                     (const unsigned short*)xlo, Wkht, Wklt, lin);
  conv_kernel<1, float><<<ROWS, 256, 0, stream>>>(lin, ck, betab, kbuf);
  mfma_gemm<<<gg, 256, 0, stream>>>((const unsigned short*)xb, Wqt, lin);
  conv_kernel<0, bf16><<<ROWS, 256, 0, stream>>>(lin, cq, betab, qbuf);
  mfma_gemm<<<gg, 256, 0, stream>>>((const unsigned short*)xb, Wvt, lin);
  conv_kernel<2, bf16><<<ROWS, 256, 0, stream>>>(lin, cv, betab, vbuf);

  // xb now dead -> kt[ch][row] bf16
  unsigned short* kt = (unsigned short*)xb;
  ktrans_kernel<<<dim3(ROWS / 64, HID / 64), 256, 0, stream>>>(kbuf, kt);

  chunkT_kernel<<<BB * NCH, 256, 0, stream>>>(kbuf, betab, Tg);
  prct_kernel<bf16><<<BB * NCH * NH, 256, 0, stream>>>(kbuf, vbuf, betab, Tg, Pb, Rb);
  scan_kernel<<<16, 256, 0, stream>>>(Pb, Rb, Sdp);
  osm_kernel<bf16><<<BB * NCH * NH, 256, 0, stream>>>(kbuf, vbuf, betab, Tg, Sdp, osmb);
  ai_kernel<bf16><<<BB * NCH, 256, 0, stream>>>(qbuf, kbuf, Aib);
  o_kernel<bf16><<<ROWS, 256, 0, stream>>>(qbuf, Sdp, osmb, Aib, g);
  mfma_gemm<<<gg, 256, 0, stream>>>((const unsigned short*)qbuf, Wot, out);

  // qbuf now dead -> Ut[bh*256+e][4096] bf16
  unsigned short* Ut = (unsigned short*)qbuf;
  ucompute_kernel<<<BB * NCH * NH * 2, 256, 0, stream>>>(kbuf, vbuf, betab, Tg,
                                                         Sdp, Ut);
  // kbuf now dead -> Spart (8 x 4MB fp32)
  float* Spart = kbuf;
  const int ngroups = 8;
  mfma_gemmS<<<dim3(2, 2, 16 * ngroups), 256, 0, stream>>>(kt, Ut, Spart, ngroups);
  sreduce_kernel<<<SSIZE / 1024, 256, 0, stream>>>(Spart, Sout, ngroups);
}